// Round 8
// baseline (782.330 us; speedup 1.0000x reference)
//
#include <hip/hip_runtime.h>
#include <hip/hip_bf16.h>

typedef short  s16x8 __attribute__((ext_vector_type(8)));
typedef float  f32x4 __attribute__((ext_vector_type(4)));

#define KBONES 64
#define HDIM   256
#define KP1    96     // padded K for layer 1 (67 -> 96)
#define BM     128    // vertices per block (mlp kernel)
#define HST    264    // LDS row stride (bf16 elems)

__device__ __forceinline__ unsigned short f2bf(float f) {
  unsigned int u = __float_as_uint(f);
  u += 0x7FFFu + ((u >> 16) & 1u);       // RNE (finite values only here)
  return (unsigned short)(u >> 16);
}
__device__ __forceinline__ float bf2f(unsigned short u) {
  union { unsigned int i; float f; } x; x.i = ((unsigned int)u) << 16; return x.f;
}

// ---------------- prep: rotation matrices + bf16-transposed weights ----------------
// rotw layout: [k][12] = {R row-major 0..8, t 9..11}
__global__ void prep_kernel(const float* __restrict__ rot6d,
                            const float* __restrict__ trans,
                            const float* __restrict__ W1,
                            const float* __restrict__ W2,
                            const float* __restrict__ W3,
                            const float* __restrict__ W4,
                            float* __restrict__ rotw,
                            unsigned short* __restrict__ W1t,
                            unsigned short* __restrict__ W2t,
                            unsigned short* __restrict__ W3t,
                            unsigned short* __restrict__ W4t) {
  int tid = blockIdx.x * blockDim.x + threadIdx.x;
  int stride = gridDim.x * blockDim.x;
  if (tid < KBONES) {
    int k = tid;
    float a10 = rot6d[k*6+0], a11 = rot6d[k*6+1], a12 = rot6d[k*6+2];
    float a20 = rot6d[k*6+3], a21 = rot6d[k*6+4], a22 = rot6d[k*6+5];
    float n1 = fmaxf(sqrtf(a10*a10 + a11*a11 + a12*a12), 1e-12f);
    float b1x = a10/n1, b1y = a11/n1, b1z = a12/n1;
    float d  = b1x*a20 + b1y*a21 + b1z*a22;
    float c0 = a20 - d*b1x, c1 = a21 - d*b1y, c2 = a22 - d*b1z;
    float n2 = fmaxf(sqrtf(c0*c0 + c1*c1 + c2*c2), 1e-12f);
    float b2x = c0/n2, b2y = c1/n2, b2z = c2/n2;
    float b3x = b1y*b2z - b1z*b2y;
    float b3y = b1z*b2x - b1x*b2z;
    float b3z = b1x*b2y - b1y*b2x;
    rotw[k*12+0]=b1x; rotw[k*12+1]=b2x; rotw[k*12+2]=b3x;
    rotw[k*12+3]=b1y; rotw[k*12+4]=b2y; rotw[k*12+5]=b3y;
    rotw[k*12+6]=b1z; rotw[k*12+7]=b2z; rotw[k*12+8]=b3z;
    rotw[k*12+9]=trans[k*3+0]; rotw[k*12+10]=trans[k*3+1]; rotw[k*12+11]=trans[k*3+2];
  }
  // W1t[h][kk]: kk 0..63 = w (W1 row 3+kk), 64..66 = local_p (W1 row kk-64), 67..95 = 0
  for (int i = tid; i < HDIM*KP1; i += stride) {
    int h = i / KP1, kk = i % KP1;
    float v = (kk < 64) ? W1[(size_t)(3+kk)*HDIM + h]
            : (kk < 67) ? W1[(size_t)(kk-64)*HDIM + h] : 0.f;
    W1t[i] = f2bf(v);
  }
  for (int i = tid; i < HDIM*HDIM; i += stride) {
    int h2 = i / HDIM, h1 = i % HDIM;
    W2t[i] = f2bf(W2[(size_t)h1*HDIM + h2]);
    W3t[i] = f2bf(W3[(size_t)h1*HDIM + h2]);
  }
  // W4t[j][h], j padded 3->16
  for (int i = tid; i < 16*HDIM; i += stride) {
    int j = i / HDIM, h = i % HDIM;
    W4t[i] = (j < 3) ? f2bf(W4[(size_t)h*3 + j]) : (unsigned short)0;
  }
}

// ---------------- per-vertex polar rotation (matches U diag(1,1,s) Vh) ----------------
__device__ __forceinline__ void polar_rotation(const float M[9], float R[9]) {
  float a00 = M[0]*M[0] + M[3]*M[3] + M[6]*M[6];
  float a01 = M[0]*M[1] + M[3]*M[4] + M[6]*M[7];
  float a02 = M[0]*M[2] + M[3]*M[5] + M[6]*M[8];
  float a11 = M[1]*M[1] + M[4]*M[4] + M[7]*M[7];
  float a12 = M[1]*M[2] + M[4]*M[5] + M[7]*M[8];
  float a22 = M[2]*M[2] + M[5]*M[5] + M[8]*M[8];
  float v00=1.f,v01=0.f,v02=0.f, v10=0.f,v11=1.f,v12=0.f, v20=0.f,v21=0.f,v22=1.f;

#define JROT(APP,AQQ,APQ,APR,AQR, VP0,VQ0, VP1,VQ1, VP2,VQ2)                     \
  {                                                                              \
    float apq = APQ;                                                             \
    if (fabsf(apq) > 1e-25f) {                                                   \
      float tau = (AQQ - APP) / (2.f * apq);                                     \
      float tt  = copysignf(1.f / (fabsf(tau) + sqrtf(1.f + tau*tau)), tau);     \
      float c   = 1.f / sqrtf(1.f + tt*tt);                                      \
      float s   = tt * c;                                                        \
      APP -= tt * apq; AQQ += tt * apq; APQ = 0.f;                               \
      float pr = APR, qr = AQR;                                                  \
      APR = c*pr - s*qr; AQR = s*pr + c*qr;                                      \
      float t0;                                                                  \
      t0 = VP0; VP0 = c*t0 - s*VQ0; VQ0 = s*t0 + c*VQ0;                          \
      t0 = VP1; VP1 = c*t0 - s*VQ1; VQ1 = s*t0 + c*VQ1;                          \
      t0 = VP2; VP2 = c*t0 - s*VQ2; VQ2 = s*t0 + c*VQ2;                          \
    }                                                                            \
  }

  #pragma unroll
  for (int sweep = 0; sweep < 5; ++sweep) {
    JROT(a00, a11, a01, a02, a12, v00,v01, v10,v11, v20,v21)
    JROT(a00, a22, a02, a01, a12, v00,v02, v10,v12, v20,v22)
    JROT(a11, a22, a12, a01, a02, v01,v02, v11,v12, v21,v22)
  }
#undef JROT

  float l0=a00, l1=a11, l2=a22;
  float e0x=v00,e0y=v10,e0z=v20;
  float e1x=v01,e1y=v11,e1z=v21;
  float e2x=v02,e2y=v12,e2z=v22;
  float tf;
  if (l0 < l1) { tf=l0;l0=l1;l1=tf; tf=e0x;e0x=e1x;e1x=tf; tf=e0y;e0y=e1y;e1y=tf; tf=e0z;e0z=e1z;e1z=tf; }
  if (l0 < l2) { tf=l0;l0=l2;l2=tf; tf=e0x;e0x=e2x;e2x=tf; tf=e0y;e0y=e2y;e2y=tf; tf=e0z;e0z=e2z;e2z=tf; }
  if (l1 < l2) { tf=l1;l1=l2;l2=tf; tf=e1x;e1x=e2x;e2x=tf; tf=e1y;e1y=e2y;e2y=tf; tf=e1z;e1z=e2z;e2z=tf; }

  float u1x = M[0]*e0x + M[1]*e0y + M[2]*e0z;
  float u1y = M[3]*e0x + M[4]*e0y + M[5]*e0z;
  float u1z = M[6]*e0x + M[7]*e0y + M[8]*e0z;
  float i1 = 1.f / fmaxf(sqrtf(u1x*u1x + u1y*u1y + u1z*u1z), 1e-25f);
  u1x*=i1; u1y*=i1; u1z*=i1;
  float u2x = M[0]*e1x + M[1]*e1y + M[2]*e1z;
  float u2y = M[3]*e1x + M[4]*e1y + M[5]*e1z;
  float u2z = M[6]*e1x + M[7]*e1y + M[8]*e1z;
  float dd = u1x*u2x + u1y*u2y + u1z*u2z;
  u2x -= dd*u1x; u2y -= dd*u1y; u2z -= dd*u1z;
  float i2 = 1.f / fmaxf(sqrtf(u2x*u2x + u2y*u2y + u2z*u2z), 1e-25f);
  u2x*=i2; u2y*=i2; u2z*=i2;
  float u3x = u1y*u2z - u1z*u2y;
  float u3y = u1z*u2x - u1x*u2z;
  float u3z = u1x*u2y - u1y*u2x;
  float w2x = e0y*e1z - e0z*e1y;
  float w2y = e0z*e1x - e0x*e1z;
  float w2z = e0x*e1y - e0y*e1x;
  R[0] = u1x*e0x + u2x*e1x + u3x*w2x;
  R[1] = u1x*e0y + u2x*e1y + u3x*w2y;
  R[2] = u1x*e0z + u2x*e1z + u3x*w2z;
  R[3] = u1y*e0x + u2y*e1x + u3y*w2x;
  R[4] = u1y*e0y + u2y*e1y + u3y*w2y;
  R[5] = u1y*e0z + u2y*e1z + u3y*w2z;
  R[6] = u1z*e0x + u2z*e1x + u3z*w2x;
  R[7] = u1z*e0y + u2z*e1y + u3z*w2y;
  R[8] = u1z*e0z + u2z*e1z + u3z*w2z;
}

// ---------------- kernel 2: one thread per vertex (softmax, blend, SVD) ----------------
// Two-pass streaming softmax (peak ~35 live VGPRs, no spill at the compiler's
// 64-reg budget). Logits reload in pass 2 is an L2 hit.
__global__ __launch_bounds__(256) void vertex_kernel(
                              const float* __restrict__ verts,
                              const float* __restrict__ logits,
                              const float* __restrict__ rotw,
                              unsigned short* __restrict__ Xg,
                              float* __restrict__ RbS,
                              float* __restrict__ out, int N) {
  __shared__ float rotL[KBONES*12];
  const int tid = threadIdx.x;
  for (int i = tid; i < KBONES*12; i += 256) rotL[i] = rotw[i];
  __syncthreads();
  const int n = blockIdx.x * 256 + tid;
  if (n >= N) return;

  const f32x4* lg = reinterpret_cast<const f32x4*>(logits + (size_t)n * KBONES);

  float ssum = 0.f;
  #pragma unroll 1
  for (int i = 0; i < 16; ++i) {
    const f32x4 z = lg[i];
    ssum += __expf(z[0]) + __expf(z[1]) + __expf(z[2]) + __expf(z[3]);
  }
  const float inv = 1.f / ssum;

  float M0=0.f,M1=0.f,M2=0.f,M3=0.f,M4=0.f,M5=0.f,M6=0.f,M7=0.f,M8=0.f;
  float tb0=0.f, tb1=0.f, tb2=0.f;
  unsigned short* xr = Xg + (size_t)n * KP1;
  #pragma unroll 1
  for (int c = 0; c < 8; ++c) {
    const f32x4 za = lg[2*c];
    const f32x4 zb = lg[2*c+1];
    s16x8 sv;
    #pragma unroll
    for (int j = 0; j < 8; ++j) {
      const float zz = (j < 4) ? za[j] : zb[j-4];
      const float w = __expf(zz) * inv;
      sv[j] = (short)f2bf(w);
      const f32x4 r0 = *reinterpret_cast<const f32x4*>(&rotL[(c*8+j)*12]);
      const f32x4 r1 = *reinterpret_cast<const f32x4*>(&rotL[(c*8+j)*12+4]);
      const f32x4 r2 = *reinterpret_cast<const f32x4*>(&rotL[(c*8+j)*12+8]);
      M0+=w*r0[0]; M1+=w*r0[1]; M2+=w*r0[2];
      M3+=w*r0[3]; M4+=w*r1[0]; M5+=w*r1[1];
      M6+=w*r1[2]; M7+=w*r1[3]; M8+=w*r2[0];
      tb0+=w*r2[1]; tb1+=w*r2[2]; tb2+=w*r2[3];
    }
    *reinterpret_cast<s16x8*>(xr + c*8) = sv;
  }

  float M[9] = {M0,M1,M2,M3,M4,M5,M6,M7,M8};
  const float vx = verts[(size_t)n*3+0], vy = verts[(size_t)n*3+1], vz = verts[(size_t)n*3+2];
  const float p0 = M[0]*vx + M[1]*vy + M[2]*vz;   // Mv = skinned - t_b
  const float p1 = M[3]*vx + M[4]*vy + M[5]*vz;
  const float p2 = M[6]*vx + M[7]*vy + M[8]*vz;
  float R[9];
  polar_rotation(M, R);
  // local_p = R^T (Mv)
  s16x8 t8 = { (short)f2bf(R[0]*p0 + R[3]*p1 + R[6]*p2),
               (short)f2bf(R[1]*p0 + R[4]*p1 + R[7]*p2),
               (short)f2bf(R[2]*p0 + R[5]*p1 + R[8]*p2), 0,0,0,0,0 };
  *reinterpret_cast<s16x8*>(xr + 64) = t8;
  const s16x8 z8 = {0,0,0,0,0,0,0,0};
  *reinterpret_cast<s16x8*>(xr + 72) = z8;
  *reinterpret_cast<s16x8*>(xr + 80) = z8;
  *reinterpret_cast<s16x8*>(xr + 88) = z8;

  const float s0 = p0 + tb0, s1 = p1 + tb1, s2 = p2 + tb2;
  f32x4 rb0 = {R[0], R[1], R[2], R[3]};
  f32x4 rb1 = {R[4], R[5], R[6], R[7]};
  f32x4 rb2 = {R[8], s0, s1, s2};
  float* rr = RbS + (size_t)n * 12;
  *reinterpret_cast<f32x4*>(rr)     = rb0;
  *reinterpret_cast<f32x4*>(rr + 4) = rb1;
  *reinterpret_cast<f32x4*>(rr + 8) = rb2;

  const size_t o = (size_t)N*3 + (size_t)n*3;
  out[o+0] = s0; out[o+1] = s1; out[o+2] = s2;
}

// ---------------- kernel 3: MLP via bf16 MFMA, 64h x 32v wave tiles, 16 waves ----------------
// Occupancy is the lever (r4 vs r7: time doubles when waves/SIMD halves at the
// 128-reg quantum). 64h x 32v: per K-step = 4 A-loads + 2 LDS B-reads + 8 MFMA
// (65 FLOP/LDS-byte -> MFMA-bound) with only 32 acc regs; total ~100 regs fits
// the (1024,4) 128-reg cap -> no spill AND 4 waves/SIMD. unroll 2 bounds
// prefetch-hoisting so the allocator can't balloon past 128 (round-6 lesson).
__global__ __launch_bounds__(1024, 4) void mlp_kernel(
    const unsigned short* __restrict__ Xg,
    const unsigned short* __restrict__ W1t,
    const unsigned short* __restrict__ W2t,
    const unsigned short* __restrict__ W3t,
    const unsigned short* __restrict__ W4t,
    const float* __restrict__ b1p, const float* __restrict__ b2p,
    const float* __restrict__ b3p, const float* __restrict__ b4p,
    const float* __restrict__ RbS,
    float* __restrict__ out, int N) {

  __shared__ __align__(16) unsigned short Hs[BM][HST];  // 67584 B
  __shared__ float dLb[BM][4];                          // 2048 B

  const int tid = threadIdx.x;
  const int vbase = blockIdx.x * BM;

  // stage X tile into cols 0..95 (zero-fill rows >= N); 1536 chunks, 1024 threads
  #pragma unroll
  for (int it = 0; it < 2; ++it) {
    const int c = tid + it*1024;
    if (c < 1536) {
      const int r = c / 12, cc = c % 12;
      s16x8 v = {0,0,0,0,0,0,0,0};
      if (vbase + r < N)
        v = *reinterpret_cast<const s16x8*>(Xg + (size_t)(vbase + r)*KP1 + cc*8);
      *reinterpret_cast<s16x8*>(&Hs[r][cc*8]) = v;
    }
  }
  __syncthreads();

  const int wid  = tid >> 6;         // 0..15
  const int lane = tid & 63;
  const int lrow = lane & 15;
  const int hq   = lane >> 4;
  const int kof  = hq * 8;
  const int hb   = (wid & 3) * 64;   // wave's 64 h-rows
  const int vb   = (wid >> 2) * 32;  // wave's 32 vertex-cols

  f32x4 acc[4][2];                   // [h-subtile t][v-subtile v] = 32 regs

#define MLP_LAYER(WPTR, BPTR, KDIM, KSN)                                         \
  {                                                                              \
    _Pragma("unroll")                                                            \
    for (int t = 0; t < 4; ++t) {                                                \
      const f32x4 bias = *reinterpret_cast<const f32x4*>(BPTR + hb + t*16 + hq*4);\
      acc[t][0] = bias; acc[t][1] = bias;                                        \
    }                                                                            \
    _Pragma("unroll 2")                                                          \
    for (int ks = 0; ks < KSN; ++ks) {                                           \
      const int k0 = kof + 32*ks;                                                \
      s16x8 a0 = *reinterpret_cast<const s16x8*>(WPTR + (size_t)(hb +      lrow)*KDIM + k0); \
      s16x8 a1 = *reinterpret_cast<const s16x8*>(WPTR + (size_t)(hb + 16 + lrow)*KDIM + k0); \
      s16x8 a2 = *reinterpret_cast<const s16x8*>(WPTR + (size_t)(hb + 32 + lrow)*KDIM + k0); \
      s16x8 a3 = *reinterpret_cast<const s16x8*>(WPTR + (size_t)(hb + 48 + lrow)*KDIM + k0); \
      const s16x8 b0 = *reinterpret_cast<const s16x8*>(&Hs[vb +      lrow][k0]); \
      const s16x8 b1 = *reinterpret_cast<const s16x8*>(&Hs[vb + 16 + lrow][k0]); \
      acc[0][0] = __builtin_amdgcn_mfma_f32_16x16x32_bf16(a0, b0, acc[0][0], 0, 0, 0); \
      acc[1][0] = __builtin_amdgcn_mfma_f32_16x16x32_bf16(a1, b0, acc[1][0], 0, 0, 0); \
      acc[2][0] = __builtin_amdgcn_mfma_f32_16x16x32_bf16(a2, b0, acc[2][0], 0, 0, 0); \
      acc[3][0] = __builtin_amdgcn_mfma_f32_16x16x32_bf16(a3, b0, acc[3][0], 0, 0, 0); \
      acc[0][1] = __builtin_amdgcn_mfma_f32_16x16x32_bf16(a0, b1, acc[0][1], 0, 0, 0); \
      acc[1][1] = __builtin_amdgcn_mfma_f32_16x16x32_bf16(a1, b1, acc[1][1], 0, 0, 0); \
      acc[2][1] = __builtin_amdgcn_mfma_f32_16x16x32_bf16(a2, b1, acc[2][1], 0, 0, 0); \
      acc[3][1] = __builtin_amdgcn_mfma_f32_16x16x32_bf16(a3, b1, acc[3][1], 0, 0, 0); \
    }                                                                            \
  }

#define EPILOGUE()                                                               \
  {                                                                              \
    _Pragma("unroll")                                                            \
    for (int t = 0; t < 4; ++t) {                                                \
      _Pragma("unroll")                                                          \
      for (int v = 0; v < 2; ++v) {                                              \
        f32x4 a = acc[t][v];                                                     \
        float2 lo2; lo2.x = fmaxf(a[0], 0.f); lo2.y = fmaxf(a[1], 0.f);          \
        float2 hi2; hi2.x = fmaxf(a[2], 0.f); hi2.y = fmaxf(a[3], 0.f);          \
        union { __hip_bfloat162 h; unsigned int u; } cl, ch;                     \
        cl.h = __float22bfloat162_rn(lo2);                                       \
        ch.h = __float22bfloat162_rn(hi2);                                       \
        uint2 pk; pk.x = cl.u; pk.y = ch.u;                                      \
        *reinterpret_cast<uint2*>(&Hs[vb + v*16 + lrow][hb + t*16 + hq*4]) = pk; \
      }                                                                          \
    }                                                                            \
  }

  // ---- layer 1: K=96 ----
  MLP_LAYER(W1t, b1p, KP1, 3)
  __syncthreads();     // all X reads done before H1 overwrites cols 0..95
  EPILOGUE()
  __syncthreads();

  // ---- layer 2: K=256 ----
  MLP_LAYER(W2t, b2p, HDIM, 8)
  __syncthreads();
  EPILOGUE()
  __syncthreads();

  // ---- layer 3: K=256 ----
  MLP_LAYER(W3t, b3p, HDIM, 8)
  __syncthreads();
  EPILOGUE()
  __syncthreads();
#undef MLP_LAYER
#undef EPILOGUE

  // ---- layer 4 (256 -> 3 padded to 16): waves 0..7, vertex rows wid*16+lrow ----
  if (wid < 8) {
    f32x4 a4 = {0.f, 0.f, 0.f, 0.f};
    if (hq == 0) { a4[0] = b4p[0]; a4[1] = b4p[1]; a4[2] = b4p[2]; }
    #pragma unroll
    for (int ks = 0; ks < 8; ++ks) {
      const int k0 = kof + 32*ks;
      const s16x8 a = *reinterpret_cast<const s16x8*>(W4t + (size_t)lrow * HDIM + k0);
      const s16x8 b = *reinterpret_cast<const s16x8*>(&Hs[wid*16 + lrow][k0]);
      a4 = __builtin_amdgcn_mfma_f32_16x16x32_bf16(a, b, a4, 0, 0, 0);
    }
    if (hq == 0) {   // lanes hq==0 hold rows j=0..3 (j<3 valid) of vertex wid*16+lrow
      dLb[wid*16 + lrow][0] = a4[0];
      dLb[wid*16 + lrow][1] = a4[1];
      dLb[wid*16 + lrow][2] = a4[2];
    }
  }
  __syncthreads();

  // ---- final: tanh, rotate back, write posed + delta ----
  if (tid < BM) {
    const int n = vbase + tid;
    if (n < N) {
      const float* rr = RbS + (size_t)n * 12;
      f32x4 q0 = *reinterpret_cast<const f32x4*>(rr);
      f32x4 q1 = *reinterpret_cast<const f32x4*>(rr + 4);
      f32x4 q2 = *reinterpret_cast<const f32x4*>(rr + 8);
      const float dl0 = 0.02f * tanhf(dLb[tid][0]);
      const float dl1 = 0.02f * tanhf(dLb[tid][1]);
      const float dl2 = 0.02f * tanhf(dLb[tid][2]);
      const float dw0 = q0[0]*dl0 + q0[1]*dl1 + q0[2]*dl2;
      const float dw1 = q0[3]*dl0 + q1[0]*dl1 + q1[1]*dl2;
      const float dw2 = q1[2]*dl0 + q1[3]*dl1 + q2[0]*dl2;
      const float s0 = q2[1], s1 = q2[2], s2 = q2[3];
      const size_t o  = (size_t)n * 3;
      const size_t NB = (size_t)N * 3;
      out[o+0]      = s0 + dw0; out[o+1]      = s1 + dw1; out[o+2]      = s2 + dw2;
      out[2*NB+o+0] = dw0;      out[2*NB+o+1] = dw1;      out[2*NB+o+2] = dw2;
    }
  }
}

// ---------------- fallback: fused kernel (small workspace) ----------------
__global__ __launch_bounds__(512, 2) void deform_fused_kernel(
    const float* __restrict__ verts,
    const float* __restrict__ logits,
    const float* __restrict__ rotw,
    const unsigned short* __restrict__ W1t,
    const unsigned short* __restrict__ W2t,
    const unsigned short* __restrict__ W3t,
    const float* __restrict__ b1p, const float* __restrict__ b2p, const float* __restrict__ b3p,
    const float* __restrict__ W4, const float* __restrict__ b4p,
    float* __restrict__ out, int N) {

  __shared__ __align__(16) unsigned short Hbuf[BM][HST];
  __shared__ float rotL[KBONES*12];
  __shared__ float RbL[BM][9];
  __shared__ float skL[BM][3];

  const int tid = threadIdx.x;
  for (int i = tid; i < KBONES*12; i += 512) rotL[i] = rotw[i];
  __syncthreads();

  const int vbase = blockIdx.x * BM;

  if (tid < BM) {
    const int n = vbase + tid;
    if (n < N) {
      const float* lgp = logits + (size_t)n * KBONES;
      float ssum = 0.f;
      #pragma unroll 1
      for (int i = 0; i < 16; ++i) {
        const f32x4 z = reinterpret_cast<const f32x4*>(lgp)[i];
        ssum += __expf(z[0]) + __expf(z[1]) + __expf(z[2]) + __expf(z[3]);
      }
      float inv = 1.f / ssum;
      float M[9] = {0,0,0,0,0,0,0,0,0};
      float tb0 = 0.f, tb1 = 0.f, tb2 = 0.f;
      #pragma unroll 1
      for (int c = 0; c < 8; ++c) {
        const f32x4 za = reinterpret_cast<const f32x4*>(lgp)[2*c];
        const f32x4 zb = reinterpret_cast<const f32x4*>(lgp)[2*c+1];
        s16x8 sv;
        #pragma unroll
        for (int j = 0; j < 8; ++j) {
          const float zz = (j < 4) ? za[j] : zb[j-4];
          const float w = __expf(zz) * inv;
          sv[j] = (short)f2bf(w);
          const float* rk = &rotL[(c*8+j)*12];
          M[0] += w*rk[0]; M[1] += w*rk[1]; M[2] += w*rk[2];
          M[3] += w*rk[3]; M[4] += w*rk[4]; M[5] += w*rk[5];
          M[6] += w*rk[6]; M[7] += w*rk[7]; M[8] += w*rk[8];
          tb0 += w*rk[9]; tb1 += w*rk[10]; tb2 += w*rk[11];
        }
        *reinterpret_cast<s16x8*>(&Hbuf[tid][c*8]) = sv;
      }
      float vx = verts[(size_t)n*3+0], vy = verts[(size_t)n*3+1], vz = verts[(size_t)n*3+2];
      float p0 = M[0]*vx + M[1]*vy + M[2]*vz;
      float p1 = M[3]*vx + M[4]*vy + M[5]*vz;
      float p2 = M[6]*vx + M[7]*vy + M[8]*vz;
      float R[9];
      polar_rotation(M, R);
      const s16x8 z8 = {0,0,0,0,0,0,0,0};
      #pragma unroll
      for (int i = 8; i < 12; ++i) *reinterpret_cast<s16x8*>(&Hbuf[tid][i*8]) = z8;
      Hbuf[tid][64] = f2bf(R[0]*p0 + R[3]*p1 + R[6]*p2);
      Hbuf[tid][65] = f2bf(R[1]*p0 + R[4]*p1 + R[7]*p2);
      Hbuf[tid][66] = f2bf(R[2]*p0 + R[5]*p1 + R[8]*p2);
      #pragma unroll
      for (int e = 0; e < 9; ++e) RbL[tid][e] = R[e];
      skL[tid][0] = p0 + tb0; skL[tid][1] = p1 + tb1; skL[tid][2] = p2 + tb2;
    } else {
      const s16x8 z8 = {0,0,0,0,0,0,0,0};
      #pragma unroll
      for (int i = 0; i < 12; ++i) *reinterpret_cast<s16x8*>(&Hbuf[tid][i*8]) = z8;
    }
  }
  __syncthreads();

  const int wave = tid >> 6;
  const int lane = tid & 63;
  const int lrow = lane & 15;
  const int lkof = (lane >> 4) * 8;
  const int c0 = (wave*2+0)*16 + lrow;
  const int c1 = (wave*2+1)*16 + lrow;
  const f32x4 zf = {0.f,0.f,0.f,0.f};
  f32x4 acc[8][2];

  #pragma unroll
  for (int mt = 0; mt < 8; ++mt) { acc[mt][0] = zf; acc[mt][1] = zf; }
  #pragma unroll
  for (int ks = 0; ks < 3; ++ks) {
    const int kb = ks*32 + lkof;
    s16x8 bf0 = *reinterpret_cast<const s16x8*>(W1t + (size_t)c0 * KP1 + kb);
    s16x8 bf1 = *reinterpret_cast<const s16x8*>(W1t + (size_t)c1 * KP1 + kb);
    #pragma unroll
    for (int mt = 0; mt < 8; ++mt) {
      s16x8 af = *reinterpret_cast<const s16x8*>(&Hbuf[mt*16 + lrow][kb]);
      acc[mt][0] = __builtin_amdgcn_mfma_f32_16x16x32_bf16(af, bf0, acc[mt][0], 0, 0, 0);
      acc[mt][1] = __builtin_amdgcn_mfma_f32_16x16x32_bf16(af, bf1, acc[mt][1], 0, 0, 0);
    }
  }
  __syncthreads();
  {
    const float bb0 = b1p[c0], bb1 = b1p[c1];
    #pragma unroll
    for (int mt = 0; mt < 8; ++mt) {
      const int rbase = mt*16 + (lane>>4)*4;
      #pragma unroll
      for (int r = 0; r < 4; ++r) {
        Hbuf[rbase+r][c0] = f2bf(fmaxf(acc[mt][0][r] + bb0, 0.f));
        Hbuf[rbase+r][c1] = f2bf(fmaxf(acc[mt][1][r] + bb1, 0.f));
      }
    }
  }
  __syncthreads();

  for (int layer = 0; layer < 2; ++layer) {
    const unsigned short* Wt = (layer == 0) ? W2t : W3t;
    const float* bp = (layer == 0) ? b2p : b3p;
    #pragma unroll
    for (int mt = 0; mt < 8; ++mt) { acc[mt][0] = zf; acc[mt][1] = zf; }
    #pragma unroll
    for (int ks = 0; ks < 8; ++ks) {
      const int kb = ks*32 + lkof;
      s16x8 bf0 = *reinterpret_cast<const s16x8*>(Wt + (size_t)c0 * HDIM + kb);
      s16x8 bf1 = *reinterpret_cast<const s16x8*>(Wt + (size_t)c1 * HDIM + kb);
      #pragma unroll
      for (int mt = 0; mt < 8; ++mt) {
        s16x8 af = *reinterpret_cast<const s16x8*>(&Hbuf[mt*16 + lrow][kb]);
        acc[mt][0] = __builtin_amdgcn_mfma_f32_16x16x32_bf16(af, bf0, acc[mt][0], 0, 0, 0);
        acc[mt][1] = __builtin_amdgcn_mfma_f32_16x16x32_bf16(af, bf1, acc[mt][1], 0, 0, 0);
      }
    }
    __syncthreads();
    const float bb0 = bp[c0], bb1 = bp[c1];
    #pragma unroll
    for (int mt = 0; mt < 8; ++mt) {
      const int rbase = mt*16 + (lane>>4)*4;
      #pragma unroll
      for (int r = 0; r < 4; ++r) {
        Hbuf[rbase+r][c0] = f2bf(fmaxf(acc[mt][0][r] + bb0, 0.f));
        Hbuf[rbase+r][c1] = f2bf(fmaxf(acc[mt][1][r] + bb1, 0.f));
      }
    }
    __syncthreads();
  }

  if (tid < BM) {
    const int n = vbase + tid;
    if (n < N) {
      float d0 = b4p[0], d1 = b4p[1], d2 = b4p[2];
      const s16x8* hp = reinterpret_cast<const s16x8*>(&Hbuf[tid][0]);
      #pragma unroll
      for (int i = 0; i < 32; ++i) {
        s16x8 h8 = hp[i];
        #pragma unroll
        for (int j = 0; j < 8; ++j) {
          const float h = bf2f((unsigned short)h8[j]);
          const int c = i*8 + j;
          d0 += h * W4[c*3+0];
          d1 += h * W4[c*3+1];
          d2 += h * W4[c*3+2];
        }
      }
      const float dl0 = 0.02f * tanhf(d0);
      const float dl1 = 0.02f * tanhf(d1);
      const float dl2 = 0.02f * tanhf(d2);
      float R[9];
      #pragma unroll
      for (int e = 0; e < 9; ++e) R[e] = RbL[tid][e];
      const float dw0 = R[0]*dl0 + R[1]*dl1 + R[2]*dl2;
      const float dw1 = R[3]*dl0 + R[4]*dl1 + R[5]*dl2;
      const float dw2 = R[6]*dl0 + R[7]*dl1 + R[8]*dl2;
      const float s0 = skL[tid][0], s1 = skL[tid][1], s2 = skL[tid][2];
      const size_t o  = (size_t)n * 3;
      const size_t NB = (size_t)N * 3;
      out[o+0]      = s0 + dw0; out[o+1]      = s1 + dw1; out[o+2]      = s2 + dw2;
      out[NB+o+0]   = s0;       out[NB+o+1]   = s1;       out[NB+o+2]   = s2;
      out[2*NB+o+0] = dw0;      out[2*NB+o+1] = dw1;      out[2*NB+o+2] = dw2;
    }
  }
}

extern "C" void kernel_launch(void* const* d_in, const int* in_sizes, int n_in,
                              void* d_out, int out_size, void* d_ws, size_t ws_size,
                              hipStream_t stream) {
  const float* verts  = (const float*)d_in[0];
  const float* logits = (const float*)d_in[1];
  const float* rot6d  = (const float*)d_in[2];
  const float* trans  = (const float*)d_in[3];
  const float* W1 = (const float*)d_in[4];
  const float* b1 = (const float*)d_in[5];
  const float* W2 = (const float*)d_in[6];
  const float* b2 = (const float*)d_in[7];
  const float* W3 = (const float*)d_in[8];
  const float* b3 = (const float*)d_in[9];
  const float* W4 = (const float*)d_in[10];
  const float* b4 = (const float*)d_in[11];
  float* out = (float*)d_out;
  const int N = in_sizes[0] / 3;
  const size_t N128 = (((size_t)N + 127) / 128) * 128;

  char* ws = (char*)d_ws;
  const size_t o_rotw = 0;                         // 64*12*4 = 3072
  const size_t o_w1t  = 4096;                      // 49152
  const size_t o_w2t  = o_w1t + 49152;             // 131072
  const size_t o_w3t  = o_w2t + 131072;            // 131072
  const size_t o_w4t  = o_w3t + 131072;            // 8192
  const size_t o_rbs  = (o_w4t + 8192 + 255) & ~(size_t)255;   // N*12*4
  const size_t o_x    = (o_rbs + (size_t)N*48 + 255) & ~(size_t)255;
  const size_t need   = o_x + N128 * KP1 * 2;

  float*          rotw = (float*)(ws + o_rotw);
  unsigned short* W1t  = (unsigned short*)(ws + o_w1t);
  unsigned short* W2t  = (unsigned short*)(ws + o_w2t);
  unsigned short* W3t  = (unsigned short*)(ws + o_w3t);
  unsigned short* W4t  = (unsigned short*)(ws + o_w4t);
  float*          RbS  = (float*)(ws + o_rbs);
  unsigned short* Xg   = (unsigned short*)(ws + o_x);

  prep_kernel<<<128, 256, 0, stream>>>(rot6d, trans, W1, W2, W3, W4,
                                       rotw, W1t, W2t, W3t, W4t);

  if (ws_size >= need) {
    const int grid2 = (N + 255) / 256;
    vertex_kernel<<<grid2, 256, 0, stream>>>(verts, logits, rotw, Xg, RbS, out, N);
    const int grid3 = (int)(N128 / 128);
    mlp_kernel<<<grid3, 1024, 0, stream>>>(Xg, W1t, W2t, W3t, W4t,
                                           b1, b2, b3, b4, RbS, out, N);
  } else {
    const int grid = (N + BM - 1) / BM;
    deform_fused_kernel<<<grid, 512, 0, stream>>>(verts, logits, rotw, W1t, W2t, W3t,
                                                  b1, b2, b3, W4, b4, out, N);
  }
}

// Round 9
// 746.497 us; speedup vs baseline: 1.0480x; 1.0480x over previous
//
#include <hip/hip_runtime.h>
#include <hip/hip_bf16.h>

typedef short  s16x8 __attribute__((ext_vector_type(8)));
typedef float  f32x4 __attribute__((ext_vector_type(4)));

#define KBONES 64
#define HDIM   256
#define KP1    96     // padded K for layer 1 (67 -> 96)
#define BM     128    // vertices per block (mlp kernel)
#define HST    264    // LDS row stride (bf16 elems)

__device__ __forceinline__ unsigned short f2bf(float f) {
  unsigned int u = __float_as_uint(f);
  u += 0x7FFFu + ((u >> 16) & 1u);       // RNE (finite values only here)
  return (unsigned short)(u >> 16);
}
__device__ __forceinline__ float bf2f(unsigned short u) {
  union { unsigned int i; float f; } x; x.i = ((unsigned int)u) << 16; return x.f;
}

// ---------------- prep: rotation matrices + bf16-transposed weights ----------------
// rotw layout: [k][12] = {R row-major 0..8, t 9..11}
__global__ void prep_kernel(const float* __restrict__ rot6d,
                            const float* __restrict__ trans,
                            const float* __restrict__ W1,
                            const float* __restrict__ W2,
                            const float* __restrict__ W3,
                            const float* __restrict__ W4,
                            float* __restrict__ rotw,
                            unsigned short* __restrict__ W1t,
                            unsigned short* __restrict__ W2t,
                            unsigned short* __restrict__ W3t,
                            unsigned short* __restrict__ W4t) {
  int tid = blockIdx.x * blockDim.x + threadIdx.x;
  int stride = gridDim.x * blockDim.x;
  if (tid < KBONES) {
    int k = tid;
    float a10 = rot6d[k*6+0], a11 = rot6d[k*6+1], a12 = rot6d[k*6+2];
    float a20 = rot6d[k*6+3], a21 = rot6d[k*6+4], a22 = rot6d[k*6+5];
    float n1 = fmaxf(sqrtf(a10*a10 + a11*a11 + a12*a12), 1e-12f);
    float b1x = a10/n1, b1y = a11/n1, b1z = a12/n1;
    float d  = b1x*a20 + b1y*a21 + b1z*a22;
    float c0 = a20 - d*b1x, c1 = a21 - d*b1y, c2 = a22 - d*b1z;
    float n2 = fmaxf(sqrtf(c0*c0 + c1*c1 + c2*c2), 1e-12f);
    float b2x = c0/n2, b2y = c1/n2, b2z = c2/n2;
    float b3x = b1y*b2z - b1z*b2y;
    float b3y = b1z*b2x - b1x*b2z;
    float b3z = b1x*b2y - b1y*b2x;
    rotw[k*12+0]=b1x; rotw[k*12+1]=b2x; rotw[k*12+2]=b3x;
    rotw[k*12+3]=b1y; rotw[k*12+4]=b2y; rotw[k*12+5]=b3y;
    rotw[k*12+6]=b1z; rotw[k*12+7]=b2z; rotw[k*12+8]=b3z;
    rotw[k*12+9]=trans[k*3+0]; rotw[k*12+10]=trans[k*3+1]; rotw[k*12+11]=trans[k*3+2];
  }
  // W1t[h][kk]: kk 0..63 = w (W1 row 3+kk), 64..66 = local_p (W1 row kk-64), 67..95 = 0
  for (int i = tid; i < HDIM*KP1; i += stride) {
    int h = i / KP1, kk = i % KP1;
    float v = (kk < 64) ? W1[(size_t)(3+kk)*HDIM + h]
            : (kk < 67) ? W1[(size_t)(kk-64)*HDIM + h] : 0.f;
    W1t[i] = f2bf(v);
  }
  for (int i = tid; i < HDIM*HDIM; i += stride) {
    int h2 = i / HDIM, h1 = i % HDIM;
    W2t[i] = f2bf(W2[(size_t)h1*HDIM + h2]);
    W3t[i] = f2bf(W3[(size_t)h1*HDIM + h2]);
  }
  // W4t[j][h], j padded 3->16
  for (int i = tid; i < 16*HDIM; i += stride) {
    int j = i / HDIM, h = i % HDIM;
    W4t[i] = (j < 3) ? f2bf(W4[(size_t)h*3 + j]) : (unsigned short)0;
  }
}

// ---------------- per-vertex polar rotation (matches U diag(1,1,s) Vh) ----------------
__device__ __forceinline__ void polar_rotation(const float M[9], float R[9]) {
  float a00 = M[0]*M[0] + M[3]*M[3] + M[6]*M[6];
  float a01 = M[0]*M[1] + M[3]*M[4] + M[6]*M[7];
  float a02 = M[0]*M[2] + M[3]*M[5] + M[6]*M[8];
  float a11 = M[1]*M[1] + M[4]*M[4] + M[7]*M[7];
  float a12 = M[1]*M[2] + M[4]*M[5] + M[7]*M[8];
  float a22 = M[2]*M[2] + M[5]*M[5] + M[8]*M[8];
  float v00=1.f,v01=0.f,v02=0.f, v10=0.f,v11=1.f,v12=0.f, v20=0.f,v21=0.f,v22=1.f;

#define JROT(APP,AQQ,APQ,APR,AQR, VP0,VQ0, VP1,VQ1, VP2,VQ2)                     \
  {                                                                              \
    float apq = APQ;                                                             \
    if (fabsf(apq) > 1e-25f) {                                                   \
      float tau = (AQQ - APP) / (2.f * apq);                                     \
      float tt  = copysignf(1.f / (fabsf(tau) + sqrtf(1.f + tau*tau)), tau);     \
      float c   = 1.f / sqrtf(1.f + tt*tt);                                      \
      float s   = tt * c;                                                        \
      APP -= tt * apq; AQQ += tt * apq; APQ = 0.f;                               \
      float pr = APR, qr = AQR;                                                  \
      APR = c*pr - s*qr; AQR = s*pr + c*qr;                                      \
      float t0;                                                                  \
      t0 = VP0; VP0 = c*t0 - s*VQ0; VQ0 = s*t0 + c*VQ0;                          \
      t0 = VP1; VP1 = c*t0 - s*VQ1; VQ1 = s*t0 + c*VQ1;                          \
      t0 = VP2; VP2 = c*t0 - s*VQ2; VQ2 = s*t0 + c*VQ2;                          \
    }                                                                            \
  }

  #pragma unroll
  for (int sweep = 0; sweep < 5; ++sweep) {
    JROT(a00, a11, a01, a02, a12, v00,v01, v10,v11, v20,v21)
    JROT(a00, a22, a02, a01, a12, v00,v02, v10,v12, v20,v22)
    JROT(a11, a22, a12, a01, a02, v01,v02, v11,v12, v21,v22)
  }
#undef JROT

  float l0=a00, l1=a11, l2=a22;
  float e0x=v00,e0y=v10,e0z=v20;
  float e1x=v01,e1y=v11,e1z=v21;
  float e2x=v02,e2y=v12,e2z=v22;
  float tf;
  if (l0 < l1) { tf=l0;l0=l1;l1=tf; tf=e0x;e0x=e1x;e1x=tf; tf=e0y;e0y=e1y;e1y=tf; tf=e0z;e0z=e1z;e1z=tf; }
  if (l0 < l2) { tf=l0;l0=l2;l2=tf; tf=e0x;e0x=e2x;e2x=tf; tf=e0y;e0y=e2y;e2y=tf; tf=e0z;e0z=e2z;e2z=tf; }
  if (l1 < l2) { tf=l1;l1=l2;l2=tf; tf=e1x;e1x=e2x;e2x=tf; tf=e1y;e1y=e2y;e2y=tf; tf=e1z;e1z=e2z;e2z=tf; }

  float u1x = M[0]*e0x + M[1]*e0y + M[2]*e0z;
  float u1y = M[3]*e0x + M[4]*e0y + M[5]*e0z;
  float u1z = M[6]*e0x + M[7]*e0y + M[8]*e0z;
  float i1 = 1.f / fmaxf(sqrtf(u1x*u1x + u1y*u1y + u1z*u1z), 1e-25f);
  u1x*=i1; u1y*=i1; u1z*=i1;
  float u2x = M[0]*e1x + M[1]*e1y + M[2]*e1z;
  float u2y = M[3]*e1x + M[4]*e1y + M[5]*e1z;
  float u2z = M[6]*e1x + M[7]*e1y + M[8]*e1z;
  float dd = u1x*u2x + u1y*u2y + u1z*u2z;
  u2x -= dd*u1x; u2y -= dd*u1y; u2z -= dd*u1z;
  float i2 = 1.f / fmaxf(sqrtf(u2x*u2x + u2y*u2y + u2z*u2z), 1e-25f);
  u2x*=i2; u2y*=i2; u2z*=i2;
  float u3x = u1y*u2z - u1z*u2y;
  float u3y = u1z*u2x - u1x*u2z;
  float u3z = u1x*u2y - u1y*u2x;
  float w2x = e0y*e1z - e0z*e1y;
  float w2y = e0z*e1x - e0x*e1z;
  float w2z = e0x*e1y - e0y*e1x;
  R[0] = u1x*e0x + u2x*e1x + u3x*w2x;
  R[1] = u1x*e0y + u2x*e1y + u3x*w2y;
  R[2] = u1x*e0z + u2x*e1z + u3x*w2z;
  R[3] = u1y*e0x + u2y*e1x + u3y*w2x;
  R[4] = u1y*e0y + u2y*e1y + u3y*w2y;
  R[5] = u1y*e0z + u2y*e1z + u3y*w2z;
  R[6] = u1z*e0x + u2z*e1x + u3z*w2x;
  R[7] = u1z*e0y + u2z*e1y + u3z*w2y;
  R[8] = u1z*e0z + u2z*e1z + u3z*w2z;
}

// ---------------- kernel 2: one thread per vertex (softmax, blend, SVD) ----------------
// Two-pass streaming softmax (peak ~35 live VGPRs, no spill at the compiler's
// 64-reg budget). Logits reload in pass 2 is an L2 hit.
__global__ __launch_bounds__(256) void vertex_kernel(
                              const float* __restrict__ verts,
                              const float* __restrict__ logits,
                              const float* __restrict__ rotw,
                              unsigned short* __restrict__ Xg,
                              float* __restrict__ RbS,
                              float* __restrict__ out, int N) {
  __shared__ float rotL[KBONES*12];
  const int tid = threadIdx.x;
  for (int i = tid; i < KBONES*12; i += 256) rotL[i] = rotw[i];
  __syncthreads();
  const int n = blockIdx.x * 256 + tid;
  if (n >= N) return;

  const f32x4* lg = reinterpret_cast<const f32x4*>(logits + (size_t)n * KBONES);

  float ssum = 0.f;
  #pragma unroll 1
  for (int i = 0; i < 16; ++i) {
    const f32x4 z = lg[i];
    ssum += __expf(z[0]) + __expf(z[1]) + __expf(z[2]) + __expf(z[3]);
  }
  const float inv = 1.f / ssum;

  float M0=0.f,M1=0.f,M2=0.f,M3=0.f,M4=0.f,M5=0.f,M6=0.f,M7=0.f,M8=0.f;
  float tb0=0.f, tb1=0.f, tb2=0.f;
  unsigned short* xr = Xg + (size_t)n * KP1;
  #pragma unroll 1
  for (int c = 0; c < 8; ++c) {
    const f32x4 za = lg[2*c];
    const f32x4 zb = lg[2*c+1];
    s16x8 sv;
    #pragma unroll
    for (int j = 0; j < 8; ++j) {
      const float zz = (j < 4) ? za[j] : zb[j-4];
      const float w = __expf(zz) * inv;
      sv[j] = (short)f2bf(w);
      const f32x4 r0 = *reinterpret_cast<const f32x4*>(&rotL[(c*8+j)*12]);
      const f32x4 r1 = *reinterpret_cast<const f32x4*>(&rotL[(c*8+j)*12+4]);
      const f32x4 r2 = *reinterpret_cast<const f32x4*>(&rotL[(c*8+j)*12+8]);
      M0+=w*r0[0]; M1+=w*r0[1]; M2+=w*r0[2];
      M3+=w*r0[3]; M4+=w*r1[0]; M5+=w*r1[1];
      M6+=w*r1[2]; M7+=w*r1[3]; M8+=w*r2[0];
      tb0+=w*r2[1]; tb1+=w*r2[2]; tb2+=w*r2[3];
    }
    *reinterpret_cast<s16x8*>(xr + c*8) = sv;
  }

  float M[9] = {M0,M1,M2,M3,M4,M5,M6,M7,M8};
  const float vx = verts[(size_t)n*3+0], vy = verts[(size_t)n*3+1], vz = verts[(size_t)n*3+2];
  const float p0 = M[0]*vx + M[1]*vy + M[2]*vz;   // Mv = skinned - t_b
  const float p1 = M[3]*vx + M[4]*vy + M[5]*vz;
  const float p2 = M[6]*vx + M[7]*vy + M[8]*vz;
  float R[9];
  polar_rotation(M, R);
  // local_p = R^T (Mv)
  s16x8 t8 = { (short)f2bf(R[0]*p0 + R[3]*p1 + R[6]*p2),
               (short)f2bf(R[1]*p0 + R[4]*p1 + R[7]*p2),
               (short)f2bf(R[2]*p0 + R[5]*p1 + R[8]*p2), 0,0,0,0,0 };
  *reinterpret_cast<s16x8*>(xr + 64) = t8;
  const s16x8 z8 = {0,0,0,0,0,0,0,0};
  *reinterpret_cast<s16x8*>(xr + 72) = z8;
  *reinterpret_cast<s16x8*>(xr + 80) = z8;
  *reinterpret_cast<s16x8*>(xr + 88) = z8;

  const float s0 = p0 + tb0, s1 = p1 + tb1, s2 = p2 + tb2;
  f32x4 rb0 = {R[0], R[1], R[2], R[3]};
  f32x4 rb1 = {R[4], R[5], R[6], R[7]};
  f32x4 rb2 = {R[8], s0, s1, s2};
  float* rr = RbS + (size_t)n * 12;
  *reinterpret_cast<f32x4*>(rr)     = rb0;
  *reinterpret_cast<f32x4*>(rr + 4) = rb1;
  *reinterpret_cast<f32x4*>(rr + 8) = rb2;

  const size_t o = (size_t)N*3 + (size_t)n*3;
  out[o+0] = s0; out[o+1] = s1; out[o+2] = s2;
}

// ---------------- kernel 3: MLP via bf16 MFMA, 128h x 32v wave tiles ----------------
// LDS-port arithmetic (m134: b128 ~12 cyc/CU): round 4 (32h x 128v) issued
// 8 LDS reads per 16 MFMA -> 768 LDS-cyc vs 160 MFMA-cyc per CU per K-step,
// 4.8x LDS-bound (matches its 31.6% MfmaUtil). This tile flips the reuse:
// 2 LDS B-reads (Hs vertex frags, each feeding 8 MFMAs) + 8 global A-loads
// (W rows -> L1/L2, not the LDS port) + 16 MFMA -> 192 LDS-cyc vs 160 MFMA-cyc,
// balanced. acc stays 64 regs; frags-in-flight ~= round 4 -> same occupancy tier.
__global__ __launch_bounds__(512, 2) void mlp_kernel(
    const unsigned short* __restrict__ Xg,
    const unsigned short* __restrict__ W1t,
    const unsigned short* __restrict__ W2t,
    const unsigned short* __restrict__ W3t,
    const unsigned short* __restrict__ W4t,
    const float* __restrict__ b1p, const float* __restrict__ b2p,
    const float* __restrict__ b3p, const float* __restrict__ b4p,
    const float* __restrict__ RbS,
    float* __restrict__ out, int N) {

  __shared__ __align__(16) unsigned short Hs[BM][HST];  // 67584 B
  __shared__ float dLb[BM][4];                          // 2048 B

  const int tid = threadIdx.x;
  const int vbase = blockIdx.x * BM;

  // stage X tile into cols 0..95 (zero-fill rows >= N)
  #pragma unroll
  for (int it = 0; it < 3; ++it) {
    const int c = tid + it*512;
    const int r = c / 12, cc = c % 12;
    s16x8 v = {0,0,0,0,0,0,0,0};
    if (vbase + r < N)
      v = *reinterpret_cast<const s16x8*>(Xg + (size_t)(vbase + r)*KP1 + cc*8);
    *reinterpret_cast<s16x8*>(&Hs[r][cc*8]) = v;
  }
  __syncthreads();

  const int wid  = tid >> 6;         // 0..7
  const int lane = tid & 63;
  const int lrow = lane & 15;
  const int hq   = lane >> 4;
  const int kof  = hq * 8;
  const int hb   = (wid & 1) * 128;  // wave's 128 h-rows
  const int vb   = (wid >> 1) * 32;  // wave's 32 vertex-cols

  f32x4 acc[8][2];                   // [h-subtile t][v-subtile v] = 64 regs

#define MLP_LAYER(WPTR, BPTR, KDIM, KSN)                                         \
  {                                                                              \
    _Pragma("unroll")                                                            \
    for (int t = 0; t < 8; ++t) {                                                \
      const f32x4 bias = *reinterpret_cast<const f32x4*>(BPTR + hb + t*16 + hq*4);\
      acc[t][0] = bias; acc[t][1] = bias;                                        \
    }                                                                            \
    _Pragma("unroll 1")                                                          \
    for (int ks = 0; ks < KSN; ++ks) {                                           \
      const int k0 = kof + 32*ks;                                                \
      s16x8 a[8];                                                                \
      _Pragma("unroll")                                                          \
      for (int t = 0; t < 8; ++t)                                                \
        a[t] = *reinterpret_cast<const s16x8*>(WPTR + (size_t)(hb + t*16 + lrow)*KDIM + k0); \
      const s16x8 b0 = *reinterpret_cast<const s16x8*>(&Hs[vb +      lrow][k0]); \
      const s16x8 b1 = *reinterpret_cast<const s16x8*>(&Hs[vb + 16 + lrow][k0]); \
      _Pragma("unroll")                                                          \
      for (int t = 0; t < 8; ++t) {                                              \
        acc[t][0] = __builtin_amdgcn_mfma_f32_16x16x32_bf16(a[t], b0, acc[t][0], 0, 0, 0); \
        acc[t][1] = __builtin_amdgcn_mfma_f32_16x16x32_bf16(a[t], b1, acc[t][1], 0, 0, 0); \
      }                                                                          \
    }                                                                            \
  }

#define EPILOGUE()                                                               \
  {                                                                              \
    _Pragma("unroll")                                                            \
    for (int t = 0; t < 8; ++t) {                                                \
      _Pragma("unroll")                                                          \
      for (int v = 0; v < 2; ++v) {                                              \
        f32x4 a = acc[t][v];                                                     \
        float2 lo2; lo2.x = fmaxf(a[0], 0.f); lo2.y = fmaxf(a[1], 0.f);          \
        float2 hi2; hi2.x = fmaxf(a[2], 0.f); hi2.y = fmaxf(a[3], 0.f);          \
        union { __hip_bfloat162 h; unsigned int u; } cl, ch;                     \
        cl.h = __float22bfloat162_rn(lo2);                                       \
        ch.h = __float22bfloat162_rn(hi2);                                       \
        uint2 pk; pk.x = cl.u; pk.y = ch.u;                                      \
        *reinterpret_cast<uint2*>(&Hs[vb + v*16 + lrow][hb + t*16 + hq*4]) = pk; \
      }                                                                          \
    }                                                                            \
  }

  // ---- layer 1: K=96 ----
  MLP_LAYER(W1t, b1p, KP1, 3)
  __syncthreads();     // all X reads done before H1 overwrites cols 0..95
  EPILOGUE()
  __syncthreads();

  // ---- layer 2: K=256 ----
  MLP_LAYER(W2t, b2p, HDIM, 8)
  __syncthreads();
  EPILOGUE()
  __syncthreads();

  // ---- layer 3: K=256 ----
  MLP_LAYER(W3t, b3p, HDIM, 8)
  __syncthreads();
  EPILOGUE()
  __syncthreads();
#undef MLP_LAYER
#undef EPILOGUE

  // ---- layer 4 (256 -> 3 padded to 16): wave wid handles vertices wid*16+lrow ----
  {
    f32x4 a4 = {0.f, 0.f, 0.f, 0.f};
    if (hq == 0) { a4[0] = b4p[0]; a4[1] = b4p[1]; a4[2] = b4p[2]; }
    #pragma unroll
    for (int ks = 0; ks < 8; ++ks) {
      const int k0 = kof + 32*ks;
      const s16x8 a = *reinterpret_cast<const s16x8*>(W4t + (size_t)lrow * HDIM + k0);
      const s16x8 b = *reinterpret_cast<const s16x8*>(&Hs[wid*16 + lrow][k0]);
      a4 = __builtin_amdgcn_mfma_f32_16x16x32_bf16(a, b, a4, 0, 0, 0);
    }
    if (hq == 0) {   // lanes hq==0 hold rows j=0..3 (j<3 valid) of vertex wid*16+lrow
      dLb[wid*16 + lrow][0] = a4[0];
      dLb[wid*16 + lrow][1] = a4[1];
      dLb[wid*16 + lrow][2] = a4[2];
    }
  }
  __syncthreads();

  // ---- final: tanh, rotate back, write posed + delta ----
  if (tid < BM) {
    const int n = vbase + tid;
    if (n < N) {
      const float* rr = RbS + (size_t)n * 12;
      f32x4 q0 = *reinterpret_cast<const f32x4*>(rr);
      f32x4 q1 = *reinterpret_cast<const f32x4*>(rr + 4);
      f32x4 q2 = *reinterpret_cast<const f32x4*>(rr + 8);
      const float dl0 = 0.02f * tanhf(dLb[tid][0]);
      const float dl1 = 0.02f * tanhf(dLb[tid][1]);
      const float dl2 = 0.02f * tanhf(dLb[tid][2]);
      const float dw0 = q0[0]*dl0 + q0[1]*dl1 + q0[2]*dl2;
      const float dw1 = q0[3]*dl0 + q1[0]*dl1 + q1[1]*dl2;
      const float dw2 = q1[2]*dl0 + q1[3]*dl1 + q2[0]*dl2;
      const float s0 = q2[1], s1 = q2[2], s2 = q2[3];
      const size_t o  = (size_t)n * 3;
      const size_t NB = (size_t)N * 3;
      out[o+0]      = s0 + dw0; out[o+1]      = s1 + dw1; out[o+2]      = s2 + dw2;
      out[2*NB+o+0] = dw0;      out[2*NB+o+1] = dw1;      out[2*NB+o+2] = dw2;
    }
  }
}

// ---------------- fallback: fused kernel (small workspace) ----------------
__global__ __launch_bounds__(512, 2) void deform_fused_kernel(
    const float* __restrict__ verts,
    const float* __restrict__ logits,
    const float* __restrict__ rotw,
    const unsigned short* __restrict__ W1t,
    const unsigned short* __restrict__ W2t,
    const unsigned short* __restrict__ W3t,
    const float* __restrict__ b1p, const float* __restrict__ b2p, const float* __restrict__ b3p,
    const float* __restrict__ W4, const float* __restrict__ b4p,
    float* __restrict__ out, int N) {

  __shared__ __align__(16) unsigned short Hbuf[BM][HST];
  __shared__ float rotL[KBONES*12];
  __shared__ float RbL[BM][9];
  __shared__ float skL[BM][3];

  const int tid = threadIdx.x;
  for (int i = tid; i < KBONES*12; i += 512) rotL[i] = rotw[i];
  __syncthreads();

  const int vbase = blockIdx.x * BM;

  if (tid < BM) {
    const int n = vbase + tid;
    if (n < N) {
      const float* lgp = logits + (size_t)n * KBONES;
      float ssum = 0.f;
      #pragma unroll 1
      for (int i = 0; i < 16; ++i) {
        const f32x4 z = reinterpret_cast<const f32x4*>(lgp)[i];
        ssum += __expf(z[0]) + __expf(z[1]) + __expf(z[2]) + __expf(z[3]);
      }
      float inv = 1.f / ssum;
      float M[9] = {0,0,0,0,0,0,0,0,0};
      float tb0 = 0.f, tb1 = 0.f, tb2 = 0.f;
      #pragma unroll 1
      for (int c = 0; c < 8; ++c) {
        const f32x4 za = reinterpret_cast<const f32x4*>(lgp)[2*c];
        const f32x4 zb = reinterpret_cast<const f32x4*>(lgp)[2*c+1];
        s16x8 sv;
        #pragma unroll
        for (int j = 0; j < 8; ++j) {
          const float zz = (j < 4) ? za[j] : zb[j-4];
          const float w = __expf(zz) * inv;
          sv[j] = (short)f2bf(w);
          const float* rk = &rotL[(c*8+j)*12];
          M[0] += w*rk[0]; M[1] += w*rk[1]; M[2] += w*rk[2];
          M[3] += w*rk[3]; M[4] += w*rk[4]; M[5] += w*rk[5];
          M[6] += w*rk[6]; M[7] += w*rk[7]; M[8] += w*rk[8];
          tb0 += w*rk[9]; tb1 += w*rk[10]; tb2 += w*rk[11];
        }
        *reinterpret_cast<s16x8*>(&Hbuf[tid][c*8]) = sv;
      }
      float vx = verts[(size_t)n*3+0], vy = verts[(size_t)n*3+1], vz = verts[(size_t)n*3+2];
      float p0 = M[0]*vx + M[1]*vy + M[2]*vz;
      float p1 = M[3]*vx + M[4]*vy + M[5]*vz;
      float p2 = M[6]*vx + M[7]*vy + M[8]*vz;
      float R[9];
      polar_rotation(M, R);
      const s16x8 z8 = {0,0,0,0,0,0,0,0};
      #pragma unroll
      for (int i = 8; i < 12; ++i) *reinterpret_cast<s16x8*>(&Hbuf[tid][i*8]) = z8;
      Hbuf[tid][64] = f2bf(R[0]*p0 + R[3]*p1 + R[6]*p2);
      Hbuf[tid][65] = f2bf(R[1]*p0 + R[4]*p1 + R[7]*p2);
      Hbuf[tid][66] = f2bf(R[2]*p0 + R[5]*p1 + R[8]*p2);
      #pragma unroll
      for (int e = 0; e < 9; ++e) RbL[tid][e] = R[e];
      skL[tid][0] = p0 + tb0; skL[tid][1] = p1 + tb1; skL[tid][2] = p2 + tb2;
    } else {
      const s16x8 z8 = {0,0,0,0,0,0,0,0};
      #pragma unroll
      for (int i = 0; i < 12; ++i) *reinterpret_cast<s16x8*>(&Hbuf[tid][i*8]) = z8;
    }
  }
  __syncthreads();

  const int wave = tid >> 6;
  const int lane = tid & 63;
  const int lrow = lane & 15;
  const int lkof = (lane >> 4) * 8;
  const int c0 = (wave*2+0)*16 + lrow;
  const int c1 = (wave*2+1)*16 + lrow;
  const f32x4 zf = {0.f,0.f,0.f,0.f};
  f32x4 acc[8][2];

  #pragma unroll
  for (int mt = 0; mt < 8; ++mt) { acc[mt][0] = zf; acc[mt][1] = zf; }
  #pragma unroll
  for (int ks = 0; ks < 3; ++ks) {
    const int kb = ks*32 + lkof;
    s16x8 bf0 = *reinterpret_cast<const s16x8*>(W1t + (size_t)c0 * KP1 + kb);
    s16x8 bf1 = *reinterpret_cast<const s16x8*>(W1t + (size_t)c1 * KP1 + kb);
    #pragma unroll
    for (int mt = 0; mt < 8; ++mt) {
      s16x8 af = *reinterpret_cast<const s16x8*>(&Hbuf[mt*16 + lrow][kb]);
      acc[mt][0] = __builtin_amdgcn_mfma_f32_16x16x32_bf16(af, bf0, acc[mt][0], 0, 0, 0);
      acc[mt][1] = __builtin_amdgcn_mfma_f32_16x16x32_bf16(af, bf1, acc[mt][1], 0, 0, 0);
    }
  }
  __syncthreads();
  {
    const float bb0 = b1p[c0], bb1 = b1p[c1];
    #pragma unroll
    for (int mt = 0; mt < 8; ++mt) {
      const int rbase = mt*16 + (lane>>4)*4;
      #pragma unroll
      for (int r = 0; r < 4; ++r) {
        Hbuf[rbase+r][c0] = f2bf(fmaxf(acc[mt][0][r] + bb0, 0.f));
        Hbuf[rbase+r][c1] = f2bf(fmaxf(acc[mt][1][r] + bb1, 0.f));
      }
    }
  }
  __syncthreads();

  for (int layer = 0; layer < 2; ++layer) {
    const unsigned short* Wt = (layer == 0) ? W2t : W3t;
    const float* bp = (layer == 0) ? b2p : b3p;
    #pragma unroll
    for (int mt = 0; mt < 8; ++mt) { acc[mt][0] = zf; acc[mt][1] = zf; }
    #pragma unroll
    for (int ks = 0; ks < 8; ++ks) {
      const int kb = ks*32 + lkof;
      s16x8 bf0 = *reinterpret_cast<const s16x8*>(Wt + (size_t)c0 * HDIM + kb);
      s16x8 bf1 = *reinterpret_cast<const s16x8*>(Wt + (size_t)c1 * HDIM + kb);
      #pragma unroll
      for (int mt = 0; mt < 8; ++mt) {
        s16x8 af = *reinterpret_cast<const s16x8*>(&Hbuf[mt*16 + lrow][kb]);
        acc[mt][0] = __builtin_amdgcn_mfma_f32_16x16x32_bf16(af, bf0, acc[mt][0], 0, 0, 0);
        acc[mt][1] = __builtin_amdgcn_mfma_f32_16x16x32_bf16(af, bf1, acc[mt][1], 0, 0, 0);
      }
    }
    __syncthreads();
    const float bb0 = bp[c0], bb1 = bp[c1];
    #pragma unroll
    for (int mt = 0; mt < 8; ++mt) {
      const int rbase = mt*16 + (lane>>4)*4;
      #pragma unroll
      for (int r = 0; r < 4; ++r) {
        Hbuf[rbase+r][c0] = f2bf(fmaxf(acc[mt][0][r] + bb0, 0.f));
        Hbuf[rbase+r][c1] = f2bf(fmaxf(acc[mt][1][r] + bb1, 0.f));
      }
    }
    __syncthreads();
  }

  if (tid < BM) {
    const int n = vbase + tid;
    if (n < N) {
      float d0 = b4p[0], d1 = b4p[1], d2 = b4p[2];
      const s16x8* hp = reinterpret_cast<const s16x8*>(&Hbuf[tid][0]);
      #pragma unroll
      for (int i = 0; i < 32; ++i) {
        s16x8 h8 = hp[i];
        #pragma unroll
        for (int j = 0; j < 8; ++j) {
          const float h = bf2f((unsigned short)h8[j]);
          const int c = i*8 + j;
          d0 += h * W4[c*3+0];
          d1 += h * W4[c*3+1];
          d2 += h * W4[c*3+2];
        }
      }
      const float dl0 = 0.02f * tanhf(d0);
      const float dl1 = 0.02f * tanhf(d1);
      const float dl2 = 0.02f * tanhf(d2);
      float R[9];
      #pragma unroll
      for (int e = 0; e < 9; ++e) R[e] = RbL[tid][e];
      const float dw0 = R[0]*dl0 + R[1]*dl1 + R[2]*dl2;
      const float dw1 = R[3]*dl0 + R[4]*dl1 + R[5]*dl2;
      const float dw2 = R[6]*dl0 + R[7]*dl1 + R[8]*dl2;
      const float s0 = skL[tid][0], s1 = skL[tid][1], s2 = skL[tid][2];
      const size_t o  = (size_t)n * 3;
      const size_t NB = (size_t)N * 3;
      out[o+0]      = s0 + dw0; out[o+1]      = s1 + dw1; out[o+2]      = s2 + dw2;
      out[NB+o+0]   = s0;       out[NB+o+1]   = s1;       out[NB+o+2]   = s2;
      out[2*NB+o+0] = dw0;      out[2*NB+o+1] = dw1;      out[2*NB+o+2] = dw2;
    }
  }
}

extern "C" void kernel_launch(void* const* d_in, const int* in_sizes, int n_in,
                              void* d_out, int out_size, void* d_ws, size_t ws_size,
                              hipStream_t stream) {
  const float* verts  = (const float*)d_in[0];
  const float* logits = (const float*)d_in[1];
  const float* rot6d  = (const float*)d_in[2];
  const float* trans  = (const float*)d_in[3];
  const float* W1 = (const float*)d_in[4];
  const float* b1 = (const float*)d_in[5];
  const float* W2 = (const float*)d_in[6];
  const float* b2 = (const float*)d_in[7];
  const float* W3 = (const float*)d_in[8];
  const float* b3 = (const float*)d_in[9];
  const float* W4 = (const float*)d_in[10];
  const float* b4 = (const float*)d_in[11];
  float* out = (float*)d_out;
  const int N = in_sizes[0] / 3;
  const size_t N128 = (((size_t)N + 127) / 128) * 128;

  char* ws = (char*)d_ws;
  const size_t o_rotw = 0;                         // 64*12*4 = 3072
  const size_t o_w1t  = 4096;                      // 49152
  const size_t o_w2t  = o_w1t + 49152;             // 131072
  const size_t o_w3t  = o_w2t + 131072;            // 131072
  const size_t o_w4t  = o_w3t + 131072;            // 8192
  const size_t o_rbs  = (o_w4t + 8192 + 255) & ~(size_t)255;   // N*12*4
  const size_t o_x    = (o_rbs + (size_t)N*48 + 255) & ~(size_t)255;
  const size_t need   = o_x + N128 * KP1 * 2;

  float*          rotw = (float*)(ws + o_rotw);
  unsigned short* W1t  = (unsigned short*)(ws + o_w1t);
  unsigned short* W2t  = (unsigned short*)(ws + o_w2t);
  unsigned short* W3t  = (unsigned short*)(ws + o_w3t);
  unsigned short* W4t  = (unsigned short*)(ws + o_w4t);
  float*          RbS  = (float*)(ws + o_rbs);
  unsigned short* Xg   = (unsigned short*)(ws + o_x);

  prep_kernel<<<128, 256, 0, stream>>>(rot6d, trans, W1, W2, W3, W4,
                                       rotw, W1t, W2t, W3t, W4t);

  if (ws_size >= need) {
    const int grid2 = (N + 255) / 256;
    vertex_kernel<<<grid2, 256, 0, stream>>>(verts, logits, rotw, Xg, RbS, out, N);
    const int grid3 = (int)(N128 / 128);
    mlp_kernel<<<grid3, 512, 0, stream>>>(Xg, W1t, W2t, W3t, W4t,
                                          b1, b2, b3, b4, RbS, out, N);
  } else {
    const int grid = (N + BM - 1) / BM;
    deform_fused_kernel<<<grid, 512, 0, stream>>>(verts, logits, rotw, W1t, W2t, W3t,
                                                  b1, b2, b3, W4, b4, out, N);
  }
}

// Round 10
// 379.500 us; speedup vs baseline: 2.0615x; 1.9671x over previous
//
#include <hip/hip_runtime.h>
#include <hip/hip_bf16.h>

typedef short  s16x8 __attribute__((ext_vector_type(8)));
typedef float  f32x4 __attribute__((ext_vector_type(4)));

#define KBONES 64
#define HDIM   256
#define KP1    96     // padded K for layer 1 (67 -> 96)
#define BM     128    // vertices per block (mlp kernel)
#define HST    264    // LDS row stride (bf16 elems)

__device__ __forceinline__ unsigned short f2bf(float f) {
  unsigned int u = __float_as_uint(f);
  u += 0x7FFFu + ((u >> 16) & 1u);       // RNE (finite values only here)
  return (unsigned short)(u >> 16);
}
__device__ __forceinline__ float bf2f(unsigned short u) {
  union { unsigned int i; float f; } x; x.i = ((unsigned int)u) << 16; return x.f;
}

// ---------------- prep: rotation matrices + bf16-transposed weights ----------------
// rotw layout: [k][12] = {R row-major 0..8, t 9..11}
__global__ void prep_kernel(const float* __restrict__ rot6d,
                            const float* __restrict__ trans,
                            const float* __restrict__ W1,
                            const float* __restrict__ W2,
                            const float* __restrict__ W3,
                            const float* __restrict__ W4,
                            float* __restrict__ rotw,
                            unsigned short* __restrict__ W1t,
                            unsigned short* __restrict__ W2t,
                            unsigned short* __restrict__ W3t,
                            unsigned short* __restrict__ W4t) {
  int tid = blockIdx.x * blockDim.x + threadIdx.x;
  int stride = gridDim.x * blockDim.x;
  if (tid < KBONES) {
    int k = tid;
    float a10 = rot6d[k*6+0], a11 = rot6d[k*6+1], a12 = rot6d[k*6+2];
    float a20 = rot6d[k*6+3], a21 = rot6d[k*6+4], a22 = rot6d[k*6+5];
    float n1 = fmaxf(sqrtf(a10*a10 + a11*a11 + a12*a12), 1e-12f);
    float b1x = a10/n1, b1y = a11/n1, b1z = a12/n1;
    float d  = b1x*a20 + b1y*a21 + b1z*a22;
    float c0 = a20 - d*b1x, c1 = a21 - d*b1y, c2 = a22 - d*b1z;
    float n2 = fmaxf(sqrtf(c0*c0 + c1*c1 + c2*c2), 1e-12f);
    float b2x = c0/n2, b2y = c1/n2, b2z = c2/n2;
    float b3x = b1y*b2z - b1z*b2y;
    float b3y = b1z*b2x - b1x*b2z;
    float b3z = b1x*b2y - b1y*b2x;
    rotw[k*12+0]=b1x; rotw[k*12+1]=b2x; rotw[k*12+2]=b3x;
    rotw[k*12+3]=b1y; rotw[k*12+4]=b2y; rotw[k*12+5]=b3y;
    rotw[k*12+6]=b1z; rotw[k*12+7]=b2z; rotw[k*12+8]=b3z;
    rotw[k*12+9]=trans[k*3+0]; rotw[k*12+10]=trans[k*3+1]; rotw[k*12+11]=trans[k*3+2];
  }
  // W1t[h][kk]: kk 0..63 = w (W1 row 3+kk), 64..66 = local_p (W1 row kk-64), 67..95 = 0
  for (int i = tid; i < HDIM*KP1; i += stride) {
    int h = i / KP1, kk = i % KP1;
    float v = (kk < 64) ? W1[(size_t)(3+kk)*HDIM + h]
            : (kk < 67) ? W1[(size_t)(kk-64)*HDIM + h] : 0.f;
    W1t[i] = f2bf(v);
  }
  for (int i = tid; i < HDIM*HDIM; i += stride) {
    int h2 = i / HDIM, h1 = i % HDIM;
    W2t[i] = f2bf(W2[(size_t)h1*HDIM + h2]);
    W3t[i] = f2bf(W3[(size_t)h1*HDIM + h2]);
  }
  // W4t[j][h], j padded 3->16
  for (int i = tid; i < 16*HDIM; i += stride) {
    int j = i / HDIM, h = i % HDIM;
    W4t[i] = (j < 3) ? f2bf(W4[(size_t)h*3 + j]) : (unsigned short)0;
  }
}

// ---------------- per-vertex polar rotation (matches U diag(1,1,s) Vh) ----------------
__device__ __forceinline__ void polar_rotation(const float M[9], float R[9]) {
  float a00 = M[0]*M[0] + M[3]*M[3] + M[6]*M[6];
  float a01 = M[0]*M[1] + M[3]*M[4] + M[6]*M[7];
  float a02 = M[0]*M[2] + M[3]*M[5] + M[6]*M[8];
  float a11 = M[1]*M[1] + M[4]*M[4] + M[7]*M[7];
  float a12 = M[1]*M[2] + M[4]*M[5] + M[7]*M[8];
  float a22 = M[2]*M[2] + M[5]*M[5] + M[8]*M[8];
  float v00=1.f,v01=0.f,v02=0.f, v10=0.f,v11=1.f,v12=0.f, v20=0.f,v21=0.f,v22=1.f;

#define JROT(APP,AQQ,APQ,APR,AQR, VP0,VQ0, VP1,VQ1, VP2,VQ2)                     \
  {                                                                              \
    float apq = APQ;                                                             \
    if (fabsf(apq) > 1e-25f) {                                                   \
      float tau = (AQQ - APP) / (2.f * apq);                                     \
      float tt  = copysignf(1.f / (fabsf(tau) + sqrtf(1.f + tau*tau)), tau);     \
      float c   = 1.f / sqrtf(1.f + tt*tt);                                      \
      float s   = tt * c;                                                        \
      APP -= tt * apq; AQQ += tt * apq; APQ = 0.f;                               \
      float pr = APR, qr = AQR;                                                  \
      APR = c*pr - s*qr; AQR = s*pr + c*qr;                                      \
      float t0;                                                                  \
      t0 = VP0; VP0 = c*t0 - s*VQ0; VQ0 = s*t0 + c*VQ0;                          \
      t0 = VP1; VP1 = c*t0 - s*VQ1; VQ1 = s*t0 + c*VQ1;                          \
      t0 = VP2; VP2 = c*t0 - s*VQ2; VQ2 = s*t0 + c*VQ2;                          \
    }                                                                            \
  }

  #pragma unroll
  for (int sweep = 0; sweep < 5; ++sweep) {
    JROT(a00, a11, a01, a02, a12, v00,v01, v10,v11, v20,v21)
    JROT(a00, a22, a02, a01, a12, v00,v02, v10,v12, v20,v22)
    JROT(a11, a22, a12, a01, a02, v01,v02, v11,v12, v21,v22)
  }
#undef JROT

  float l0=a00, l1=a11, l2=a22;
  float e0x=v00,e0y=v10,e0z=v20;
  float e1x=v01,e1y=v11,e1z=v21;
  float e2x=v02,e2y=v12,e2z=v22;
  float tf;
  if (l0 < l1) { tf=l0;l0=l1;l1=tf; tf=e0x;e0x=e1x;e1x=tf; tf=e0y;e0y=e1y;e1y=tf; tf=e0z;e0z=e1z;e1z=tf; }
  if (l0 < l2) { tf=l0;l0=l2;l2=tf; tf=e0x;e0x=e2x;e2x=tf; tf=e0y;e0y=e2y;e2y=tf; tf=e0z;e0z=e2z;e2z=tf; }
  if (l1 < l2) { tf=l1;l1=l2;l2=tf; tf=e1x;e1x=e2x;e2x=tf; tf=e1y;e1y=e2y;e2y=tf; tf=e1z;e1z=e2z;e2z=tf; }

  float u1x = M[0]*e0x + M[1]*e0y + M[2]*e0z;
  float u1y = M[3]*e0x + M[4]*e0y + M[5]*e0z;
  float u1z = M[6]*e0x + M[7]*e0y + M[8]*e0z;
  float i1 = 1.f / fmaxf(sqrtf(u1x*u1x + u1y*u1y + u1z*u1z), 1e-25f);
  u1x*=i1; u1y*=i1; u1z*=i1;
  float u2x = M[0]*e1x + M[1]*e1y + M[2]*e1z;
  float u2y = M[3]*e1x + M[4]*e1y + M[5]*e1z;
  float u2z = M[6]*e1x + M[7]*e1y + M[8]*e1z;
  float dd = u1x*u2x + u1y*u2y + u1z*u2z;
  u2x -= dd*u1x; u2y -= dd*u1y; u2z -= dd*u1z;
  float i2 = 1.f / fmaxf(sqrtf(u2x*u2x + u2y*u2y + u2z*u2z), 1e-25f);
  u2x*=i2; u2y*=i2; u2z*=i2;
  float u3x = u1y*u2z - u1z*u2y;
  float u3y = u1z*u2x - u1x*u2z;
  float u3z = u1x*u2y - u1y*u2x;
  float w2x = e0y*e1z - e0z*e1y;
  float w2y = e0z*e1x - e0x*e1z;
  float w2z = e0x*e1y - e0y*e1x;
  R[0] = u1x*e0x + u2x*e1x + u3x*w2x;
  R[1] = u1x*e0y + u2x*e1y + u3x*w2y;
  R[2] = u1x*e0z + u2x*e1z + u3x*w2z;
  R[3] = u1y*e0x + u2y*e1x + u3y*w2x;
  R[4] = u1y*e0y + u2y*e1y + u3y*w2y;
  R[5] = u1y*e0z + u2y*e1z + u3y*w2z;
  R[6] = u1z*e0x + u2z*e1x + u3z*w2x;
  R[7] = u1z*e0y + u2z*e1y + u3z*w2y;
  R[8] = u1z*e0z + u2z*e1z + u3z*w2z;
}

// ---------------- kernel 2: one thread per vertex (softmax, blend, SVD) ----------------
// Two-pass streaming softmax (peak ~35 live VGPRs, no spill at the compiler's
// 64-reg budget). Logits reload in pass 2 is an L2 hit. [r4 empirical best]
__global__ __launch_bounds__(256) void vertex_kernel(
                              const float* __restrict__ verts,
                              const float* __restrict__ logits,
                              const float* __restrict__ rotw,
                              unsigned short* __restrict__ Xg,
                              float* __restrict__ RbS,
                              float* __restrict__ out, int N) {
  __shared__ float rotL[KBONES*12];
  const int tid = threadIdx.x;
  for (int i = tid; i < KBONES*12; i += 256) rotL[i] = rotw[i];
  __syncthreads();
  const int n = blockIdx.x * 256 + tid;
  if (n >= N) return;

  const f32x4* lg = reinterpret_cast<const f32x4*>(logits + (size_t)n * KBONES);

  float ssum = 0.f;
  #pragma unroll 1
  for (int i = 0; i < 16; ++i) {
    const f32x4 z = lg[i];
    ssum += __expf(z[0]) + __expf(z[1]) + __expf(z[2]) + __expf(z[3]);
  }
  const float inv = 1.f / ssum;

  float M0=0.f,M1=0.f,M2=0.f,M3=0.f,M4=0.f,M5=0.f,M6=0.f,M7=0.f,M8=0.f;
  float tb0=0.f, tb1=0.f, tb2=0.f;
  unsigned short* xr = Xg + (size_t)n * KP1;
  #pragma unroll 1
  for (int c = 0; c < 8; ++c) {
    const f32x4 za = lg[2*c];
    const f32x4 zb = lg[2*c+1];
    s16x8 sv;
    #pragma unroll
    for (int j = 0; j < 8; ++j) {
      const float zz = (j < 4) ? za[j] : zb[j-4];
      const float w = __expf(zz) * inv;
      sv[j] = (short)f2bf(w);
      const f32x4 r0 = *reinterpret_cast<const f32x4*>(&rotL[(c*8+j)*12]);
      const f32x4 r1 = *reinterpret_cast<const f32x4*>(&rotL[(c*8+j)*12+4]);
      const f32x4 r2 = *reinterpret_cast<const f32x4*>(&rotL[(c*8+j)*12+8]);
      M0+=w*r0[0]; M1+=w*r0[1]; M2+=w*r0[2];
      M3+=w*r0[3]; M4+=w*r1[0]; M5+=w*r1[1];
      M6+=w*r1[2]; M7+=w*r1[3]; M8+=w*r2[0];
      tb0+=w*r2[1]; tb1+=w*r2[2]; tb2+=w*r2[3];
    }
    *reinterpret_cast<s16x8*>(xr + c*8) = sv;
  }

  float M[9] = {M0,M1,M2,M3,M4,M5,M6,M7,M8};
  const float vx = verts[(size_t)n*3+0], vy = verts[(size_t)n*3+1], vz = verts[(size_t)n*3+2];
  const float p0 = M[0]*vx + M[1]*vy + M[2]*vz;   // Mv = skinned - t_b
  const float p1 = M[3]*vx + M[4]*vy + M[5]*vz;
  const float p2 = M[6]*vx + M[7]*vy + M[8]*vz;
  float R[9];
  polar_rotation(M, R);
  // local_p = R^T (Mv)
  s16x8 t8 = { (short)f2bf(R[0]*p0 + R[3]*p1 + R[6]*p2),
               (short)f2bf(R[1]*p0 + R[4]*p1 + R[7]*p2),
               (short)f2bf(R[2]*p0 + R[5]*p1 + R[8]*p2), 0,0,0,0,0 };
  *reinterpret_cast<s16x8*>(xr + 64) = t8;
  const s16x8 z8 = {0,0,0,0,0,0,0,0};
  *reinterpret_cast<s16x8*>(xr + 72) = z8;
  *reinterpret_cast<s16x8*>(xr + 80) = z8;
  *reinterpret_cast<s16x8*>(xr + 88) = z8;

  const float s0 = p0 + tb0, s1 = p1 + tb1, s2 = p2 + tb2;
  f32x4 rb0 = {R[0], R[1], R[2], R[3]};
  f32x4 rb1 = {R[4], R[5], R[6], R[7]};
  f32x4 rb2 = {R[8], s0, s1, s2};
  float* rr = RbS + (size_t)n * 12;
  *reinterpret_cast<f32x4*>(rr)     = rb0;
  *reinterpret_cast<f32x4*>(rr + 4) = rb1;
  *reinterpret_cast<f32x4*>(rr + 8) = rb2;

  const size_t o = (size_t)N*3 + (size_t)n*3;
  out[o+0] = s0; out[o+1] = s1; out[o+2] = s2;
}

// ---------------- kernel 3: MLP via bf16 MFMA [r4 empirical best: 223 us] ----------------
// 32h x 128v wave tile, 2 W-cols per wave, full K-unroll. 56 VGPR + 64 AGPR =
// 120 unified regs -> 16 waves/CU tier. Rounds 5-9 refuted every alternative:
// (r5) epilogue swap -5%; (r6/r7) 64x64 -> 140 regs -> occupancy cliff;
// (r8) small tiles -> no per-wave ILP; (r9) unroll-1 global-W -> latency-bound.
__global__ __launch_bounds__(512, 2) void mlp_kernel(
    const unsigned short* __restrict__ Xg,
    const unsigned short* __restrict__ W1t,
    const unsigned short* __restrict__ W2t,
    const unsigned short* __restrict__ W3t,
    const unsigned short* __restrict__ W4t,
    const float* __restrict__ b1p, const float* __restrict__ b2p,
    const float* __restrict__ b3p, const float* __restrict__ b4p,
    const float* __restrict__ RbS,
    float* __restrict__ out, int N) {

  __shared__ __align__(16) unsigned short Hbuf[BM][HST];  // 67584 B
  __shared__ float dL[BM][4];                             // 2048 B

  const int tid = threadIdx.x;
  const int vbase = blockIdx.x * BM;

  // stage X tile (zero-fill rows >= N)
  #pragma unroll
  for (int it = 0; it < 3; ++it) {
    const int c = tid + it*512;
    const int r = c / 12, cc = c % 12;
    s16x8 v = {0,0,0,0,0,0,0,0};
    if (vbase + r < N)
      v = __builtin_nontemporal_load(
            reinterpret_cast<const s16x8*>(Xg + (size_t)(vbase + r)*KP1 + cc*8));
    *reinterpret_cast<s16x8*>(&Hbuf[r][cc*8]) = v;
  }
  __syncthreads();

  const int wave = tid >> 6;
  const int lane = tid & 63;
  const int lrow = lane & 15;
  const int lkof = (lane >> 4) * 8;
  const int c0 = (wave*2+0)*16 + lrow;
  const int c1 = (wave*2+1)*16 + lrow;
  const f32x4 zf = {0.f,0.f,0.f,0.f};

  f32x4 acc[8][2];

  // ---- layer 1: K=96 ----
  #pragma unroll
  for (int mt = 0; mt < 8; ++mt) { acc[mt][0] = zf; acc[mt][1] = zf; }
  #pragma unroll
  for (int ks = 0; ks < 3; ++ks) {
    const int kb = ks*32 + lkof;
    s16x8 bf0 = *reinterpret_cast<const s16x8*>(W1t + (size_t)c0 * KP1 + kb);
    s16x8 bf1 = *reinterpret_cast<const s16x8*>(W1t + (size_t)c1 * KP1 + kb);
    #pragma unroll
    for (int mt = 0; mt < 8; ++mt) {
      s16x8 af = *reinterpret_cast<const s16x8*>(&Hbuf[mt*16 + lrow][kb]);
      acc[mt][0] = __builtin_amdgcn_mfma_f32_16x16x32_bf16(af, bf0, acc[mt][0], 0, 0, 0);
      acc[mt][1] = __builtin_amdgcn_mfma_f32_16x16x32_bf16(af, bf1, acc[mt][1], 0, 0, 0);
    }
  }
  __syncthreads();
  {
    const float bb0 = b1p[c0], bb1 = b1p[c1];
    #pragma unroll
    for (int mt = 0; mt < 8; ++mt) {
      const int rbase = mt*16 + (lane>>4)*4;
      #pragma unroll
      for (int r = 0; r < 4; ++r) {
        Hbuf[rbase+r][c0] = f2bf(fmaxf(acc[mt][0][r] + bb0, 0.f));
        Hbuf[rbase+r][c1] = f2bf(fmaxf(acc[mt][1][r] + bb1, 0.f));
      }
    }
  }
  __syncthreads();

  // ---- layers 2 and 3: K=256 ----
  for (int layer = 0; layer < 2; ++layer) {
    const unsigned short* Wt = (layer == 0) ? W2t : W3t;
    const float* bp = (layer == 0) ? b2p : b3p;
    #pragma unroll
    for (int mt = 0; mt < 8; ++mt) { acc[mt][0] = zf; acc[mt][1] = zf; }
    #pragma unroll
    for (int ks = 0; ks < 8; ++ks) {
      const int kb = ks*32 + lkof;
      s16x8 bf0 = *reinterpret_cast<const s16x8*>(Wt + (size_t)c0 * HDIM + kb);
      s16x8 bf1 = *reinterpret_cast<const s16x8*>(Wt + (size_t)c1 * HDIM + kb);
      #pragma unroll
      for (int mt = 0; mt < 8; ++mt) {
        s16x8 af = *reinterpret_cast<const s16x8*>(&Hbuf[mt*16 + lrow][kb]);
        acc[mt][0] = __builtin_amdgcn_mfma_f32_16x16x32_bf16(af, bf0, acc[mt][0], 0, 0, 0);
        acc[mt][1] = __builtin_amdgcn_mfma_f32_16x16x32_bf16(af, bf1, acc[mt][1], 0, 0, 0);
      }
    }
    __syncthreads();
    const float bb0 = bp[c0], bb1 = bp[c1];
    #pragma unroll
    for (int mt = 0; mt < 8; ++mt) {
      const int rbase = mt*16 + (lane>>4)*4;
      #pragma unroll
      for (int r = 0; r < 4; ++r) {
        Hbuf[rbase+r][c0] = f2bf(fmaxf(acc[mt][0][r] + bb0, 0.f));
        Hbuf[rbase+r][c1] = f2bf(fmaxf(acc[mt][1][r] + bb1, 0.f));
      }
    }
    __syncthreads();
  }

  // ---- layer 4 (256 -> 3, padded to 16) via MFMA: wave w owns m-tile w ----
  {
    f32x4 a4 = zf;
    #pragma unroll
    for (int ks = 0; ks < 8; ++ks) {
      const int kb = ks*32 + lkof;
      s16x8 bf = *reinterpret_cast<const s16x8*>(W4t + (size_t)lrow * HDIM + kb);
      s16x8 af = *reinterpret_cast<const s16x8*>(&Hbuf[wave*16 + lrow][kb]);
      a4 = __builtin_amdgcn_mfma_f32_16x16x32_bf16(af, bf, a4, 0, 0, 0);
    }
    if (lrow < 3) {
      const float bb = b4p[lrow];
      #pragma unroll
      for (int r = 0; r < 4; ++r)
        dL[wave*16 + (lane>>4)*4 + r][lrow] = a4[r] + bb;
    }
  }
  __syncthreads();

  // ---- final: tanh, rotate back, write posed + delta ----
  if (tid < BM) {
    const int n = vbase + tid;
    if (n < N) {
      const float* rr = RbS + (size_t)n * 12;
      f32x4 q0 = __builtin_nontemporal_load(reinterpret_cast<const f32x4*>(rr));
      f32x4 q1 = __builtin_nontemporal_load(reinterpret_cast<const f32x4*>(rr + 4));
      f32x4 q2 = __builtin_nontemporal_load(reinterpret_cast<const f32x4*>(rr + 8));
      const float dl0 = 0.02f * tanhf(dL[tid][0]);
      const float dl1 = 0.02f * tanhf(dL[tid][1]);
      const float dl2 = 0.02f * tanhf(dL[tid][2]);
      const float dw0 = q0[0]*dl0 + q0[1]*dl1 + q0[2]*dl2;
      const float dw1 = q0[3]*dl0 + q1[0]*dl1 + q1[1]*dl2;
      const float dw2 = q1[2]*dl0 + q1[3]*dl1 + q2[0]*dl2;
      const float s0 = q2[1], s1 = q2[2], s2 = q2[3];
      const size_t o  = (size_t)n * 3;
      const size_t NB = (size_t)N * 3;
      out[o+0]      = s0 + dw0; out[o+1]      = s1 + dw1; out[o+2]      = s2 + dw2;
      out[2*NB+o+0] = dw0;      out[2*NB+o+1] = dw1;      out[2*NB+o+2] = dw2;
    }
  }
}

// ---------------- fallback: fused kernel (small workspace) ----------------
__global__ __launch_bounds__(512, 2) void deform_fused_kernel(
    const float* __restrict__ verts,
    const float* __restrict__ logits,
    const float* __restrict__ rotw,
    const unsigned short* __restrict__ W1t,
    const unsigned short* __restrict__ W2t,
    const unsigned short* __restrict__ W3t,
    const float* __restrict__ b1p, const float* __restrict__ b2p, const float* __restrict__ b3p,
    const float* __restrict__ W4, const float* __restrict__ b4p,
    float* __restrict__ out, int N) {

  __shared__ __align__(16) unsigned short Hbuf[BM][HST];
  __shared__ float rotL[KBONES*12];
  __shared__ float RbL[BM][9];
  __shared__ float skL[BM][3];

  const int tid = threadIdx.x;
  for (int i = tid; i < KBONES*12; i += 512) rotL[i] = rotw[i];
  __syncthreads();

  const int vbase = blockIdx.x * BM;

  if (tid < BM) {
    const int n = vbase + tid;
    if (n < N) {
      const float* lgp = logits + (size_t)n * KBONES;
      float ssum = 0.f;
      #pragma unroll 1
      for (int i = 0; i < 16; ++i) {
        const f32x4 z = reinterpret_cast<const f32x4*>(lgp)[i];
        ssum += __expf(z[0]) + __expf(z[1]) + __expf(z[2]) + __expf(z[3]);
      }
      float inv = 1.f / ssum;
      float M[9] = {0,0,0,0,0,0,0,0,0};
      float tb0 = 0.f, tb1 = 0.f, tb2 = 0.f;
      #pragma unroll 1
      for (int c = 0; c < 8; ++c) {
        const f32x4 za = reinterpret_cast<const f32x4*>(lgp)[2*c];
        const f32x4 zb = reinterpret_cast<const f32x4*>(lgp)[2*c+1];
        s16x8 sv;
        #pragma unroll
        for (int j = 0; j < 8; ++j) {
          const float zz = (j < 4) ? za[j] : zb[j-4];
          const float w = __expf(zz) * inv;
          sv[j] = (short)f2bf(w);
          const float* rk = &rotL[(c*8+j)*12];
          M[0] += w*rk[0]; M[1] += w*rk[1]; M[2] += w*rk[2];
          M[3] += w*rk[3]; M[4] += w*rk[4]; M[5] += w*rk[5];
          M[6] += w*rk[6]; M[7] += w*rk[7]; M[8] += w*rk[8];
          tb0 += w*rk[9]; tb1 += w*rk[10]; tb2 += w*rk[11];
        }
        *reinterpret_cast<s16x8*>(&Hbuf[tid][c*8]) = sv;
      }
      float vx = verts[(size_t)n*3+0], vy = verts[(size_t)n*3+1], vz = verts[(size_t)n*3+2];
      float p0 = M[0]*vx + M[1]*vy + M[2]*vz;
      float p1 = M[3]*vx + M[4]*vy + M[5]*vz;
      float p2 = M[6]*vx + M[7]*vy + M[8]*vz;
      float R[9];
      polar_rotation(M, R);
      const s16x8 z8 = {0,0,0,0,0,0,0,0};
      #pragma unroll
      for (int i = 8; i < 12; ++i) *reinterpret_cast<s16x8*>(&Hbuf[tid][i*8]) = z8;
      Hbuf[tid][64] = f2bf(R[0]*p0 + R[3]*p1 + R[6]*p2);
      Hbuf[tid][65] = f2bf(R[1]*p0 + R[4]*p1 + R[7]*p2);
      Hbuf[tid][66] = f2bf(R[2]*p0 + R[5]*p1 + R[8]*p2);
      #pragma unroll
      for (int e = 0; e < 9; ++e) RbL[tid][e] = R[e];
      skL[tid][0] = p0 + tb0; skL[tid][1] = p1 + tb1; skL[tid][2] = p2 + tb2;
    } else {
      const s16x8 z8 = {0,0,0,0,0,0,0,0};
      #pragma unroll
      for (int i = 0; i < 12; ++i) *reinterpret_cast<s16x8*>(&Hbuf[tid][i*8]) = z8;
    }
  }
  __syncthreads();

  const int wave = tid >> 6;
  const int lane = tid & 63;
  const int lrow = lane & 15;
  const int lkof = (lane >> 4) * 8;
  const int c0 = (wave*2+0)*16 + lrow;
  const int c1 = (wave*2+1)*16 + lrow;
  const f32x4 zf = {0.f,0.f,0.f,0.f};
  f32x4 acc[8][2];

  #pragma unroll
  for (int mt = 0; mt < 8; ++mt) { acc[mt][0] = zf; acc[mt][1] = zf; }
  #pragma unroll
  for (int ks = 0; ks < 3; ++ks) {
    const int kb = ks*32 + lkof;
    s16x8 bf0 = *reinterpret_cast<const s16x8*>(W1t + (size_t)c0 * KP1 + kb);
    s16x8 bf1 = *reinterpret_cast<const s16x8*>(W1t + (size_t)c1 * KP1 + kb);
    #pragma unroll
    for (int mt = 0; mt < 8; ++mt) {
      s16x8 af = *reinterpret_cast<const s16x8*>(&Hbuf[mt*16 + lrow][kb]);
      acc[mt][0] = __builtin_amdgcn_mfma_f32_16x16x32_bf16(af, bf0, acc[mt][0], 0, 0, 0);
      acc[mt][1] = __builtin_amdgcn_mfma_f32_16x16x32_bf16(af, bf1, acc[mt][1], 0, 0, 0);
    }
  }
  __syncthreads();
  {
    const float bb0 = b1p[c0], bb1 = b1p[c1];
    #pragma unroll
    for (int mt = 0; mt < 8; ++mt) {
      const int rbase = mt*16 + (lane>>4)*4;
      #pragma unroll
      for (int r = 0; r < 4; ++r) {
        Hbuf[rbase+r][c0] = f2bf(fmaxf(acc[mt][0][r] + bb0, 0.f));
        Hbuf[rbase+r][c1] = f2bf(fmaxf(acc[mt][1][r] + bb1, 0.f));
      }
    }
  }
  __syncthreads();

  for (int layer = 0; layer < 2; ++layer) {
    const unsigned short* Wt = (layer == 0) ? W2t : W3t;
    const float* bp = (layer == 0) ? b2p : b3p;
    #pragma unroll
    for (int mt = 0; mt < 8; ++mt) { acc[mt][0] = zf; acc[mt][1] = zf; }
    #pragma unroll
    for (int ks = 0; ks < 8; ++ks) {
      const int kb = ks*32 + lkof;
      s16x8 bf0 = *reinterpret_cast<const s16x8*>(Wt + (size_t)c0 * HDIM + kb);
      s16x8 bf1 = *reinterpret_cast<const s16x8*>(Wt + (size_t)c1 * HDIM + kb);
      #pragma unroll
      for (int mt = 0; mt < 8; ++mt) {
        s16x8 af = *reinterpret_cast<const s16x8*>(&Hbuf[mt*16 + lrow][kb]);
        acc[mt][0] = __builtin_amdgcn_mfma_f32_16x16x32_bf16(af, bf0, acc[mt][0], 0, 0, 0);
        acc[mt][1] = __builtin_amdgcn_mfma_f32_16x16x32_bf16(af, bf1, acc[mt][1], 0, 0, 0);
      }
    }
    __syncthreads();
    const float bb0 = bp[c0], bb1 = bp[c1];
    #pragma unroll
    for (int mt = 0; mt < 8; ++mt) {
      const int rbase = mt*16 + (lane>>4)*4;
      #pragma unroll
      for (int r = 0; r < 4; ++r) {
        Hbuf[rbase+r][c0] = f2bf(fmaxf(acc[mt][0][r] + bb0, 0.f));
        Hbuf[rbase+r][c1] = f2bf(fmaxf(acc[mt][1][r] + bb1, 0.f));
      }
    }
    __syncthreads();
  }

  if (tid < BM) {
    const int n = vbase + tid;
    if (n < N) {
      float d0 = b4p[0], d1 = b4p[1], d2 = b4p[2];
      const s16x8* hp = reinterpret_cast<const s16x8*>(&Hbuf[tid][0]);
      #pragma unroll
      for (int i = 0; i < 32; ++i) {
        s16x8 h8 = hp[i];
        #pragma unroll
        for (int j = 0; j < 8; ++j) {
          const float h = bf2f((unsigned short)h8[j]);
          const int c = i*8 + j;
          d0 += h * W4[c*3+0];
          d1 += h * W4[c*3+1];
          d2 += h * W4[c*3+2];
        }
      }
      const float dl0 = 0.02f * tanhf(d0);
      const float dl1 = 0.02f * tanhf(d1);
      const float dl2 = 0.02f * tanhf(d2);
      float R[9];
      #pragma unroll
      for (int e = 0; e < 9; ++e) R[e] = RbL[tid][e];
      const float dw0 = R[0]*dl0 + R[1]*dl1 + R[2]*dl2;
      const float dw1 = R[3]*dl0 + R[4]*dl1 + R[5]*dl2;
      const float dw2 = R[6]*dl0 + R[7]*dl1 + R[8]*dl2;
      const float s0 = skL[tid][0], s1 = skL[tid][1], s2 = skL[tid][2];
      const size_t o  = (size_t)n * 3;
      const size_t NB = (size_t)N * 3;
      out[o+0]      = s0 + dw0; out[o+1]      = s1 + dw1; out[o+2]      = s2 + dw2;
      out[NB+o+0]   = s0;       out[NB+o+1]   = s1;       out[NB+o+2]   = s2;
      out[2*NB+o+0] = dw0;      out[2*NB+o+1] = dw1;      out[2*NB+o+2] = dw2;
    }
  }
}

extern "C" void kernel_launch(void* const* d_in, const int* in_sizes, int n_in,
                              void* d_out, int out_size, void* d_ws, size_t ws_size,
                              hipStream_t stream) {
  const float* verts  = (const float*)d_in[0];
  const float* logits = (const float*)d_in[1];
  const float* rot6d  = (const float*)d_in[2];
  const float* trans  = (const float*)d_in[3];
  const float* W1 = (const float*)d_in[4];
  const float* b1 = (const float*)d_in[5];
  const float* W2 = (const float*)d_in[6];
  const float* b2 = (const float*)d_in[7];
  const float* W3 = (const float*)d_in[8];
  const float* b3 = (const float*)d_in[9];
  const float* W4 = (const float*)d_in[10];
  const float* b4 = (const float*)d_in[11];
  float* out = (float*)d_out;
  const int N = in_sizes[0] / 3;
  const size_t N128 = (((size_t)N + 127) / 128) * 128;

  char* ws = (char*)d_ws;
  const size_t o_rotw = 0;                         // 64*12*4 = 3072
  const size_t o_w1t  = 4096;                      // 49152
  const size_t o_w2t  = o_w1t + 49152;             // 131072
  const size_t o_w3t  = o_w2t + 131072;            // 131072
  const size_t o_w4t  = o_w3t + 131072;            // 8192
  const size_t o_rbs  = (o_w4t + 8192 + 255) & ~(size_t)255;   // N*12*4
  const size_t o_x    = (o_rbs + (size_t)N*48 + 255) & ~(size_t)255;
  const size_t need   = o_x + N128 * KP1 * 2;

  float*          rotw = (float*)(ws + o_rotw);
  unsigned short* W1t  = (unsigned short*)(ws + o_w1t);
  unsigned short* W2t  = (unsigned short*)(ws + o_w2t);
  unsigned short* W3t  = (unsigned short*)(ws + o_w3t);
  unsigned short* W4t  = (unsigned short*)(ws + o_w4t);
  float*          RbS  = (float*)(ws + o_rbs);
  unsigned short* Xg   = (unsigned short*)(ws + o_x);

  prep_kernel<<<128, 256, 0, stream>>>(rot6d, trans, W1, W2, W3, W4,
                                       rotw, W1t, W2t, W3t, W4t);

  if (ws_size >= need) {
    const int grid2 = (N + 255) / 256;
    vertex_kernel<<<grid2, 256, 0, stream>>>(verts, logits, rotw, Xg, RbS, out, N);
    const int grid3 = (int)(N128 / 128);
    mlp_kernel<<<grid3, 512, 0, stream>>>(Xg, W1t, W2t, W3t, W4t,
                                          b1, b2, b3, b4, RbS, out, N);
  } else {
    const int grid = (N + BM - 1) / BM;
    deform_fused_kernel<<<grid, 512, 0, stream>>>(verts, logits, rotw, W1t, W2t, W3t,
                                                  b1, b2, b3, W4, b4, out, N);
  }
}